// Round 13
// baseline (251.685 us; speedup 1.0000x reference)
//
#include <hip/hip_runtime.h>
#include <math.h>

#define MUL0 64
#define MUL1 32
#define RADF 8
#define HIDF 64
#define WNUM 192
#define NODE_F 160   // 64 + 96
#define AGG_F  384   // A(64) | D(32) | mv_d0(96) | mv_d1(96) | mv_d2(96)

#define INV_SQRT64 0.125f
#define INV_SQRT32 0.17677669529663687f
#define INV_SQRT8  0.35355339059327373f
#define INV_SQRT96 0.10206207261596575f
#define INV_SQRT10 0.31622776601683794f
#define INV_SQRT3  0.5773502691896258f

typedef __attribute__((ext_vector_type(8))) short bf16x8;
typedef __attribute__((ext_vector_type(4))) float f32x4;

__device__ __forceinline__ float bf2f(unsigned short u) {
    return __uint_as_float((unsigned)u << 16);
}
__device__ __forceinline__ unsigned short f2bfu(float x) {
    unsigned ua = __float_as_uint(x);
    return (unsigned short)((ua + 0x7FFF + ((ua >> 16) & 1)) >> 16);
}
__device__ __forceinline__ unsigned bf16pack(float a, float b) {
    unsigned ua = __float_as_uint(a);
    unsigned ub = __float_as_uint(b);
    ua = (ua + 0x7FFF + ((ua >> 16) & 1)) >> 16;
    ub = (ub + 0x7FFF + ((ub >> 16) & 1)) >> 16;
    return ua | (ub << 16);
}
__device__ __forceinline__ int rdlane(int v, int i) {
    return __builtin_amdgcn_readlane(v, i);
}
__device__ __forceinline__ float rdlanef(float v, int i) {
    return __int_as_float(__builtin_amdgcn_readlane(__float_as_int(v), i));
}
__device__ __forceinline__ bf16x8 cvt8(float4 a, float4 b) {
    union { unsigned q[4]; bf16x8 v; } r;
    r.q[0] = bf16pack(a.x, a.y);
    r.q[1] = bf16pack(a.z, a.w);
    r.q[2] = bf16pack(b.x, b.y);
    r.q[3] = bf16pack(b.z, b.w);
    return r.v;
}

// ---------------- kernel: f = _lin(...) via MFMA, wave per 16 nodes, bf16 output ----------------
// f layout (bf16): [n][0:64]=s ; [n][64 + d*32 + u] = v[u][d]
__global__ __launch_bounds__(256) void k_node_lin(
    const float* __restrict__ node_input,
    const float* __restrict__ node_attr,
    const float* __restrict__ W1_s,
    const float* __restrict__ W1_v,
    unsigned short* __restrict__ f, int N)
{
    __shared__ unsigned short s_w1s[8 * 64 * 8];   // 8 KB
    __shared__ unsigned short s_w1v[4 * 32 * 8];   // 2 KB
    int tid = threadIdx.x;

    for (int task = tid; task < 8 * 64; task += 256) {
        int col = task & 63, koct = task >> 6;
        const float* wp = W1_s + (size_t)(koct * 8) * MUL0 + col;
        unsigned pk0 = bf16pack(wp[0 * MUL0] * INV_SQRT64, wp[1 * MUL0] * INV_SQRT64);
        unsigned pk1 = bf16pack(wp[2 * MUL0] * INV_SQRT64, wp[3 * MUL0] * INV_SQRT64);
        unsigned pk2 = bf16pack(wp[4 * MUL0] * INV_SQRT64, wp[5 * MUL0] * INV_SQRT64);
        unsigned pk3 = bf16pack(wp[6 * MUL0] * INV_SQRT64, wp[7 * MUL0] * INV_SQRT64);
        *(uint4*)&s_w1s[task * 8] = make_uint4(pk0, pk1, pk2, pk3);
    }
    for (int task = tid; task < 4 * 32; task += 256) {
        int col = task & 31, koct = task >> 5;
        const float* wp = W1_v + (size_t)(koct * 8) * MUL1 + col;
        unsigned pk0 = bf16pack(wp[0 * MUL1] * INV_SQRT32, wp[1 * MUL1] * INV_SQRT32);
        unsigned pk1 = bf16pack(wp[2 * MUL1] * INV_SQRT32, wp[3 * MUL1] * INV_SQRT32);
        unsigned pk2 = bf16pack(wp[4 * MUL1] * INV_SQRT32, wp[5 * MUL1] * INV_SQRT32);
        unsigned pk3 = bf16pack(wp[6 * MUL1] * INV_SQRT32, wp[7 * MUL1] * INV_SQRT32);
        *(uint4*)&s_w1v[task * 8] = make_uint4(pk0, pk1, pk2, pk3);
    }
    __syncthreads();

    int lane = tid & 63;
    int wv = tid >> 6;
    int l15 = lane & 15, lh = lane >> 4;
    int ntiles = (N + 15) >> 4;

    for (int tile = blockIdx.x * 4 + wv; tile < ntiles; tile += gridDim.x * 4) {
        int n0 = tile << 4;
        int m = min(16, N - n0);
        int nrow = n0 + min(l15, m - 1);
        const float* inn = node_input + (size_t)nrow * NODE_F;

        float attr[4];
        #pragma unroll
        for (int r = 0; r < 4; ++r)
            attr[r] = node_attr[n0 + min(lh * 4 + r, m - 1)];

        bf16x8 inS[2];
        #pragma unroll
        for (int kk = 0; kk < 2; ++kk) {
            const float* p0 = inn + kk * 32 + lh * 8;
            inS[kk] = cvt8(*(const float4*)p0, *(const float4*)(p0 + 4));
        }
        #pragma unroll
        for (int cb = 0; cb < 4; ++cb) {
            f32x4 a = {0.f, 0.f, 0.f, 0.f};
            #pragma unroll
            for (int kk = 0; kk < 2; ++kk) {
                bf16x8 b = *(const bf16x8*)&s_w1s[(((kk * 4 + lh) * 64) + cb * 16 + l15) * 8];
                a = __builtin_amdgcn_mfma_f32_16x16x32_bf16(inS[kk], b, a, 0, 0, 0);
            }
            #pragma unroll
            for (int r = 0; r < 4; ++r) {
                int node = lh * 4 + r;
                if (node < m)
                    f[(size_t)(n0 + node) * NODE_F + cb * 16 + l15] = f2bfu(a[r] * attr[r]);
            }
        }

        #pragma unroll
        for (int d = 0; d < 3; ++d) {
            float t[8];
            #pragma unroll
            for (int j = 0; j < 8; ++j)
                t[j] = inn[64 + (lh * 8 + j) * 3 + d];
            bf16x8 inV = cvt8(make_float4(t[0], t[1], t[2], t[3]),
                              make_float4(t[4], t[5], t[6], t[7]));
            #pragma unroll
            for (int cb = 0; cb < 2; ++cb) {
                bf16x8 b = *(const bf16x8*)&s_w1v[((lh * 32) + cb * 16 + l15) * 8];
                f32x4 a = {0.f, 0.f, 0.f, 0.f};
                a = __builtin_amdgcn_mfma_f32_16x16x32_bf16(inV, b, a, 0, 0, 0);
                #pragma unroll
                for (int r = 0; r < 4; ++r) {
                    int node = lh * 4 + r;
                    if (node < m)
                        f[(size_t)(n0 + node) * NODE_F + 64 + d * 32 + cb * 16 + l15] =
                            f2bfu(a[r] * attr[r]);
                }
            }
        }
    }
}

// ---------------- CSR build ----------------
__global__ void k_count(const int* __restrict__ edge_dst, int* deg, int E)
{
    int e = blockIdx.x * blockDim.x + threadIdx.x;
    if (e < E) atomicAdd(&deg[edge_dst[e]], 1);
}

// multi-block scan: A = per-block local scan + block sums
__global__ __launch_bounds__(1024) void k_scan_a(const int* __restrict__ deg,
                                                 int* __restrict__ off,
                                                 int* __restrict__ bsum, int N)
{
    __shared__ int swsum[16];
    __shared__ int swoff[16];
    __shared__ int stot;
    int lane = threadIdx.x & 63, wid = threadIdx.x >> 6;
    int ng4 = (N + 3) >> 2;
    int g = blockIdx.x * 1024 + threadIdx.x;
    int4 v = make_int4(0, 0, 0, 0);
    if (g < ng4) v = ((const int4*)deg)[g];
    int s = v.x + v.y + v.z + v.w;
    int val = s;
    #pragma unroll
    for (int sh = 1; sh < 64; sh <<= 1) {
        int t = __shfl_up(val, sh);
        if (lane >= sh) val += t;
    }
    if (lane == 63) swsum[wid] = val;
    __syncthreads();
    if (threadIdx.x < 16) {
        int x = swsum[threadIdx.x];
        int xv = x;
        #pragma unroll
        for (int sh = 1; sh < 16; sh <<= 1) {
            int t = __shfl_up(xv, sh);
            if ((int)threadIdx.x >= sh) xv += t;
        }
        swoff[threadIdx.x] = xv - x;
        if (threadIdx.x == 15) stot = xv;
    }
    __syncthreads();
    if (g < ng4) {
        int b0 = swoff[wid] + (val - s);
        int4 o;
        o.x = b0; o.y = b0 + v.x; o.z = o.y + v.y; o.w = o.z + v.z;
        ((int4*)off)[g] = o;
    }
    if (threadIdx.x == 0) bsum[blockIdx.x] = stot;
}

// B: add block bases, write cur, zero agg rows of deg-0 nodes
__global__ __launch_bounds__(1024) void k_scan_b(int* __restrict__ off,
                                                 int* __restrict__ cur,
                                                 const int* __restrict__ bsum,
                                                 float* __restrict__ agg,
                                                 const int* __restrict__ deg,
                                                 int N, int nb)
{
    __shared__ int sbase;
    if (threadIdx.x == 0) {
        int s = 0;
        for (int j = 0; j < (int)blockIdx.x; ++j) s += bsum[j];
        sbase = s;
    }
    __syncthreads();
    int base = sbase;
    int ng4 = (N + 3) >> 2;
    int g = blockIdx.x * 1024 + threadIdx.x;
    if (g < ng4) {
        int4 o = ((int4*)off)[g];
        o.x += base; o.y += base; o.z += base; o.w += base;
        ((int4*)off)[g] = o;
        ((int4*)cur)[g] = o;
        int4 d = ((const int4*)deg)[g];
        int n0 = g * 4;
        #pragma unroll
        for (int q = 0; q < 4; ++q) {
            int dq = (q == 0) ? d.x : (q == 1) ? d.y : (q == 2) ? d.z : d.w;
            int nq = n0 + q;
            if (dq == 0 && nq < N) {
                float4* row = (float4*)(agg + (size_t)nq * AGG_F);
                float4 z = make_float4(0.f, 0.f, 0.f, 0.f);
                for (int j = 0; j < AGG_F / 4; ++j) row[j] = z;
            }
        }
    }
}

__global__ void k_scatter(const int* __restrict__ edge_dst,
                          int* cur, int* __restrict__ csr, int E)
{
    int e = blockIdx.x * blockDim.x + threadIdx.x;
    if (e < E) {
        int d = edge_dst[e];
        int pos = atomicAdd(&cur[d], 1);
        csr[pos] = e;
    }
}

// cut[t] = start of the dst-segment containing CSR position 16t  ->  groups hold whole segments
__global__ void k_cut(const int* __restrict__ csr, const int* __restrict__ edge_dst,
                      const int* __restrict__ off, int* __restrict__ cut, int E, int G)
{
    int t = blockIdx.x * 256 + threadIdx.x;
    if (t > G) return;
    int v;
    if (t == 0) v = 0;
    else if (t == G) v = E;
    else v = off[edge_dst[csr[t << 4]]];
    cut[t] = v;
}

// ---------------- fused edge kernel: segment-aligned groups, plain-store flush ----------------
#define STORE_AGG(node)                                              \
    do {                                                             \
        float* an = agg + (size_t)(node) * AGG_F;                    \
        an[lane] = accA;                                             \
        an[96  + lane] = accB0;                                      \
        an[192 + lane] = accB1;                                      \
        an[288 + lane] = accB2;                                      \
        if (lane < 32) {                                             \
            an[160 + u] = accX0;                                     \
            an[256 + u] = accX1;                                     \
            an[352 + u] = accX2;                                     \
        } else {                                                     \
            an[64 + u] = accX0;                                      \
        }                                                            \
    } while (0)

__global__ __launch_bounds__(256, 3) void k_edge_fused(
    const unsigned short* __restrict__ f,
    const float* __restrict__ edge_scalars,
    const float* __restrict__ edge_attr,
    const float* __restrict__ fcW1,
    const float* __restrict__ fcW2,
    const int* __restrict__ edge_src,
    const int* __restrict__ edge_dst,
    const int* __restrict__ csr,
    const int* __restrict__ cut,
    float* __restrict__ agg, int E, int G)
{
    __shared__ unsigned short s_w2t[8 * 192 * 8];   // 24576 B
    __shared__ unsigned short s_w[4][16 * 216];     // 27648 B
    __shared__ float s_fcW1[512];                   //  2048 B

    int tid  = threadIdx.x;
    int lane = tid & 63;
    int wv   = tid >> 6;
    int l15  = lane & 15, lh = lane >> 4;
    int u    = lane & 31;

    for (int task = tid; task < 1536; task += 256) {
        int col = task % 192, oct = task / 192;
        const float* wp = fcW2 + (size_t)(oct * 8) * WNUM + col;
        unsigned pk0 = bf16pack(wp[0 * WNUM], wp[1 * WNUM]);
        unsigned pk1 = bf16pack(wp[2 * WNUM], wp[3 * WNUM]);
        unsigned pk2 = bf16pack(wp[4 * WNUM], wp[5 * WNUM]);
        unsigned pk3 = bf16pack(wp[6 * WNUM], wp[7 * WNUM]);
        *(uint4*)&s_w2t[oct * 1536 + col * 8] = make_uint4(pk0, pk1, pk2, pk3);
    }
    for (int i = tid; i < 512; i += 256)
        s_fcW1[i] = fcW1[i];
    __syncthreads();      // the only block barrier

    unsigned short* sw = s_w[wv];

    for (int wt = blockIdx.x * 4 + wv; wt < G; wt += gridDim.x * 4) {
        int gbeg = cut[wt], gend = cut[wt + 1];
        if (gbeg >= gend) continue;

        float accA = 0.f, accB0 = 0.f, accB1 = 0.f, accB2 = 0.f;
        float accX0 = 0.f, accX1 = 0.f, accX2 = 0.f;
        int curd = -1;

        for (int p = gbeg; p < gend; p += 16) {
            int sz = min(16, gend - p);

            int e   = csr[p + min(l15, sz - 1)];
            int src = edge_src[e];
            int dst = edge_dst[e];
            float4 ea = *(const float4*)(edge_attr + (size_t)e * 4);
            const float4* esp = (const float4*)(edge_scalars + (size_t)e * RADF);
            float4 es0 = esp[0], es1 = esp[1];

            // ---- f gather (bf16) ----
            float xs[16], xv0[16], xv1[16], xv2[16];
            #pragma unroll
            for (int i = 0; i < 16; ++i) {
                int si = rdlane(src, i);
                const unsigned short* fb = f + (size_t)si * NODE_F;
                xs[i]  = bf2f(fb[lane]);
                xv0[i] = bf2f(fb[64 + u]);
                xv1[i] = bf2f(fb[96 + u]);
                xv2[i] = bf2f(fb[128 + u]);
            }

            // ---- h compute (registers; covers gather latency) ----
            float es[8] = {es0.x, es0.y, es0.z, es0.w, es1.x, es1.y, es1.z, es1.w};
            union { unsigned q[4]; bf16x8 v; } A0, A1;
            #pragma unroll
            for (int jp = 0; jp < 4; ++jp) {
                int k0 = lh * 8 + 2 * jp;
                float aL0 = 0.f, aL1 = 0.f, aH0 = 0.f, aH1 = 0.f;
                #pragma unroll
                for (int r = 0; r < 8; ++r) {
                    float2 wl = *(const float2*)&s_fcW1[r * 64 + k0];
                    float2 wh = *(const float2*)&s_fcW1[r * 64 + 32 + k0];
                    aL0 = fmaf(es[r], wl.x, aL0);
                    aL1 = fmaf(es[r], wl.y, aL1);
                    aH0 = fmaf(es[r], wh.x, aH0);
                    aH1 = fmaf(es[r], wh.y, aH1);
                }
                aL0 *= INV_SQRT8; aL1 *= INV_SQRT8; aH0 *= INV_SQRT8; aH1 *= INV_SQRT8;
                aL0 = aL0 / (1.f + __expf(-aL0));
                aL1 = aL1 / (1.f + __expf(-aL1));
                aH0 = aH0 / (1.f + __expf(-aH0));
                aH1 = aH1 / (1.f + __expf(-aH1));
                A0.q[jp] = bf16pack(aL0, aL1);
                A1.q[jp] = bf16pack(aH0, aH1);
            }

            // ---- MFMA: w = h @ fcW2 / sqrt(64) ----
            #pragma unroll
            for (int cb = 0; cb < 12; ++cb) {
                bf16x8 b0 = *(const bf16x8*)&s_w2t[ lh      * 1536 + (cb * 16 + l15) * 8];
                bf16x8 b1 = *(const bf16x8*)&s_w2t[(4 + lh) * 1536 + (cb * 16 + l15) * 8];
                f32x4 acc = {0.f, 0.f, 0.f, 0.f};
                acc = __builtin_amdgcn_mfma_f32_16x16x32_bf16(A0.v, b0, acc, 0, 0, 0);
                acc = __builtin_amdgcn_mfma_f32_16x16x32_bf16(A1.v, b1, acc, 0, 0, 0);
                #pragma unroll
                for (int r = 0; r < 4; ++r)
                    sw[(lh * 4 + r) * 216 + cb * 16 + l15] = f2bfu(acc[r] * INV_SQRT64);
            }

            // ---- TP + dst-segmented reduction (plain stores only) ----
            if (curd < 0) curd = rdlane(dst, 0);
            #pragma unroll
            for (int i = 0; i < 16; ++i) {
                if (i < sz) {
                    int di = rdlane(dst, i);
                    if (di != curd) {
                        STORE_AGG(curd);
                        accA = accB0 = accB1 = accB2 = 0.f;
                        accX0 = accX1 = accX2 = 0.f;
                        curd = di;
                    }
                    float eax = rdlanef(ea.x, i);
                    float eay = rdlanef(ea.y, i);
                    float eaz = rdlanef(ea.z, i);
                    float eaw = rdlanef(ea.w, i);
                    float W0 = bf2f(sw[i * 216 + lane]);
                    float W1 = bf2f(sw[i * 216 + 64 + lane]);
                    float W2 = bf2f(sw[i * 216 + 128 + lane]);
                    accA = fmaf(W0 * xs[i], eax, accA);
                    float bx = W1 * xs[i];
                    accB0 = fmaf(bx, eay, accB0);
                    accB1 = fmaf(bx, eaz, accB1);
                    accB2 = fmaf(bx, eaw, accB2);
                    if (lane < 32) {
                        float cc = W2 * eax;
                        accX0 = fmaf(cc, xv0[i], accX0);
                        accX1 = fmaf(cc, xv1[i], accX1);
                        accX2 = fmaf(cc, xv2[i], accX2);
                    } else {
                        float dv = xv0[i] * eay + xv1[i] * eaz + xv2[i] * eaw;
                        accX0 = fmaf(W2 * INV_SQRT3, dv, accX0);
                    }
                }
            }
        }
        STORE_AGG(curd);
    }
}

// ---------------- kernel: output combine via MFMA, wave per 16 nodes ----------------
__global__ __launch_bounds__(256) void k_out(
    const float* __restrict__ node_input,
    const float* __restrict__ node_attr,
    const float* __restrict__ agg,
    const float* __restrict__ W_sc_s,
    const float* __restrict__ W_sc_v,
    const float* __restrict__ W2_s,
    const float* __restrict__ W2_v,
    const float* __restrict__ W3,
    float* __restrict__ out, int N)
{
    __shared__ unsigned short s_w2s[12 * 64 * 8];   // 12288 B
    __shared__ unsigned short s_wss[ 8 * 64 * 8];   //  8192 B
    __shared__ unsigned short s_w2v[12 * 32 * 8];   //  6144 B
    __shared__ unsigned short s_wsv[ 4 * 32 * 8];   //  2048 B
    __shared__ unsigned short s_w3 [12 * 16 * 8];   //  3072 B  -> 31744 B total

    const float pre = INV_SQRT10 * INV_SQRT96;
    int tid = threadIdx.x;

    for (int task = tid; task < 12 * 64; task += 256) {         // W2_s
        int col = task & 63, koct = task >> 6;
        const float* wp = W2_s + (size_t)(koct * 8) * MUL0 + col;
        unsigned pk0 = bf16pack(wp[0 * MUL0] * pre, wp[1 * MUL0] * pre);
        unsigned pk1 = bf16pack(wp[2 * MUL0] * pre, wp[3 * MUL0] * pre);
        unsigned pk2 = bf16pack(wp[4 * MUL0] * pre, wp[5 * MUL0] * pre);
        unsigned pk3 = bf16pack(wp[6 * MUL0] * pre, wp[7 * MUL0] * pre);
        *(uint4*)&s_w2s[task * 8] = make_uint4(pk0, pk1, pk2, pk3);
    }
    for (int task = tid; task < 8 * 64; task += 256) {          // W_sc_s
        int col = task & 63, koct = task >> 6;
        const float* wp = W_sc_s + (size_t)(koct * 8) * MUL0 + col;
        unsigned pk0 = bf16pack(wp[0 * MUL0] * INV_SQRT64, wp[1 * MUL0] * INV_SQRT64);
        unsigned pk1 = bf16pack(wp[2 * MUL0] * INV_SQRT64, wp[3 * MUL0] * INV_SQRT64);
        unsigned pk2 = bf16pack(wp[4 * MUL0] * INV_SQRT64, wp[5 * MUL0] * INV_SQRT64);
        unsigned pk3 = bf16pack(wp[6 * MUL0] * INV_SQRT64, wp[7 * MUL0] * INV_SQRT64);
        *(uint4*)&s_wss[task * 8] = make_uint4(pk0, pk1, pk2, pk3);
    }
    for (int task = tid; task < 12 * 32; task += 256) {         // W2_v
        int col = task & 31, koct = task >> 5;
        const float* wp = W2_v + (size_t)(koct * 8) * MUL1 + col;
        unsigned pk0 = bf16pack(wp[0 * MUL1] * pre, wp[1 * MUL1] * pre);
        unsigned pk1 = bf16pack(wp[2 * MUL1] * pre, wp[3 * MUL1] * pre);
        unsigned pk2 = bf16pack(wp[4 * MUL1] * pre, wp[5 * MUL1] * pre);
        unsigned pk3 = bf16pack(wp[6 * MUL1] * pre, wp[7 * MUL1] * pre);
        *(uint4*)&s_w2v[task * 8] = make_uint4(pk0, pk1, pk2, pk3);
    }
    for (int task = tid; task < 4 * 32; task += 256) {          // W_sc_v
        int col = task & 31, koct = task >> 5;
        const float* wp = W_sc_v + (size_t)(koct * 8) * MUL1 + col;
        unsigned pk0 = bf16pack(wp[0 * MUL1] * INV_SQRT32, wp[1 * MUL1] * INV_SQRT32);
        unsigned pk1 = bf16pack(wp[2 * MUL1] * INV_SQRT32, wp[3 * MUL1] * INV_SQRT32);
        unsigned pk2 = bf16pack(wp[4 * MUL1] * INV_SQRT32, wp[5 * MUL1] * INV_SQRT32);
        unsigned pk3 = bf16pack(wp[6 * MUL1] * INV_SQRT32, wp[7 * MUL1] * INV_SQRT32);
        *(uint4*)&s_wsv[task * 8] = make_uint4(pk0, pk1, pk2, pk3);
    }
    for (int task = tid; task < 12 * 16; task += 256) {         // W3 block
        int col = task & 15, koct = task >> 4;
        const float sc3 = 0.1f * pre;
        unsigned pk0 = 0, pk1 = 0, pk2 = 0, pk3 = 0;
        if (col == 0) {
            const float* wp = W3 + koct * 8;
            pk0 = bf16pack(wp[0] * sc3, wp[1] * sc3);
            pk1 = bf16pack(wp[2] * sc3, wp[3] * sc3);
            pk2 = bf16pack(wp[4] * sc3, wp[5] * sc3);
            pk3 = bf16pack(wp[6] * sc3, wp[7] * sc3);
        }
        *(uint4*)&s_w3[task * 8] = make_uint4(pk0, pk1, pk2, pk3);
    }
    __syncthreads();

    int lane = tid & 63;
    int wv = tid >> 6;
    int l15 = lane & 15, lh = lane >> 4;
    int ntiles = (N + 15) >> 4;

    for (int tile = blockIdx.x * 4 + wv; tile < ntiles; tile += gridDim.x * 4) {
        int n0 = tile << 4;
        int m = min(16, N - n0);
        int nrow = n0 + min(l15, m - 1);
        const float* agn = agg + (size_t)nrow * AGG_F;
        const float* inn = node_input + (size_t)nrow * NODE_F;

        bf16x8 aggA[3], inS[2];
        #pragma unroll
        for (int kk = 0; kk < 3; ++kk) {
            const float* p0 = agn + kk * 32 + lh * 8;
            aggA[kk] = cvt8(*(const float4*)p0, *(const float4*)(p0 + 4));
        }
        #pragma unroll
        for (int kk = 0; kk < 2; ++kk) {
            const float* p0 = inn + kk * 32 + lh * 8;
            inS[kk] = cvt8(*(const float4*)p0, *(const float4*)(p0 + 4));
        }

        f32x4 convS[4], scS[4], angD = {0.f, 0.f, 0.f, 0.f};
        #pragma unroll
        for (int cb = 0; cb < 4; ++cb) {
            f32x4 a = {0.f, 0.f, 0.f, 0.f};
            #pragma unroll
            for (int kk = 0; kk < 3; ++kk) {
                bf16x8 b = *(const bf16x8*)&s_w2s[(((kk * 4 + lh) * 64) + cb * 16 + l15) * 8];
                a = __builtin_amdgcn_mfma_f32_16x16x32_bf16(aggA[kk], b, a, 0, 0, 0);
            }
            convS[cb] = a;
            f32x4 s = {0.f, 0.f, 0.f, 0.f};
            #pragma unroll
            for (int kk = 0; kk < 2; ++kk) {
                bf16x8 b = *(const bf16x8*)&s_wss[(((kk * 4 + lh) * 64) + cb * 16 + l15) * 8];
                s = __builtin_amdgcn_mfma_f32_16x16x32_bf16(inS[kk], b, s, 0, 0, 0);
            }
            scS[cb] = s;
        }
        #pragma unroll
        for (int kk = 0; kk < 3; ++kk) {
            bf16x8 b = *(const bf16x8*)&s_w3[(((kk * 4 + lh) * 16) + l15) * 8];
            angD = __builtin_amdgcn_mfma_f32_16x16x32_bf16(aggA[kk], b, angD, 0, 0, 0);
        }

        float attr[4], cs[4], sn[4];
        #pragma unroll
        for (int r = 0; r < 4; ++r) {
            attr[r] = node_attr[n0 + min(lh * 4 + r, m - 1)];
            float ang = __shfl(angD[r], lane & 48) * attr[r];
            cs[r] = cosf(ang);
            sn[r] = sinf(ang);
        }

        #pragma unroll
        for (int cb = 0; cb < 4; ++cb)
            #pragma unroll
            for (int r = 0; r < 4; ++r) {
                int node = lh * 4 + r;
                if (node < m)
                    out[(size_t)(n0 + node) * NODE_F + cb * 16 + l15] =
                        attr[r] * (cs[r] * scS[cb][r] + sn[r] * convS[cb][r]);
            }

        #pragma unroll
        for (int d = 0; d < 3; ++d) {
            bf16x8 aggV[3], inV;
            #pragma unroll
            for (int kk = 0; kk < 3; ++kk) {
                const float* p0 = agn + 96 + d * 96 + kk * 32 + lh * 8;
                aggV[kk] = cvt8(*(const float4*)p0, *(const float4*)(p0 + 4));
            }
            {
                float t[8];
                #pragma unroll
                for (int j = 0; j < 8; ++j)
                    t[j] = inn[64 + (lh * 8 + j) * 3 + d];
                inV = cvt8(make_float4(t[0], t[1], t[2], t[3]),
                           make_float4(t[4], t[5], t[6], t[7]));
            }
            #pragma unroll
            for (int cb = 0; cb < 2; ++cb) {
                f32x4 a = {0.f, 0.f, 0.f, 0.f};
                #pragma unroll
                for (int kk = 0; kk < 3; ++kk) {
                    bf16x8 b = *(const bf16x8*)&s_w2v[(((kk * 4 + lh) * 32) + cb * 16 + l15) * 8];
                    a = __builtin_amdgcn_mfma_f32_16x16x32_bf16(aggV[kk], b, a, 0, 0, 0);
                }
                f32x4 s = {0.f, 0.f, 0.f, 0.f};
                {
                    bf16x8 b = *(const bf16x8*)&s_wsv[((lh * 32) + cb * 16 + l15) * 8];
                    s = __builtin_amdgcn_mfma_f32_16x16x32_bf16(inV, b, s, 0, 0, 0);
                }
                #pragma unroll
                for (int r = 0; r < 4; ++r) {
                    int node = lh * 4 + r;
                    if (node < m)
                        out[(size_t)(n0 + node) * NODE_F + 64 + (cb * 16 + l15) * 3 + d] =
                            attr[r] * (cs[r] * s[r] + sn[r] * a[r]);
                }
            }
        }
    }
}

extern "C" void kernel_launch(void* const* d_in, const int* in_sizes, int n_in,
                              void* d_out, int out_size, void* d_ws, size_t ws_size,
                              hipStream_t stream)
{
    const float* node_input   = (const float*)d_in[0];
    const float* node_attr    = (const float*)d_in[1];
    const float* edge_attr    = (const float*)d_in[2];
    const float* edge_scalars = (const float*)d_in[3];
    const float* W_sc_s       = (const float*)d_in[4];
    const float* W_sc_v       = (const float*)d_in[5];
    const float* W1_s         = (const float*)d_in[6];
    const float* W1_v         = (const float*)d_in[7];
    const float* W2_s         = (const float*)d_in[8];
    const float* W2_v         = (const float*)d_in[9];
    const float* W3           = (const float*)d_in[10];
    const float* fcW1         = (const float*)d_in[11];
    const float* fcW2         = (const float*)d_in[12];
    const int*   edge_src     = (const int*)d_in[13];
    const int*   edge_dst     = (const int*)d_in[14];
    float* out = (float*)d_out;

    const int N = in_sizes[1];
    const int E = in_sizes[13];
    const int Np = (N + 3) & ~3;          // pad for int4 scan
    const int G = (E + 15) / 16;          // segment-aligned groups

    // ---- workspace layout ----
    char* p = (char*)d_ws;
    float* agg = (float*)p;            p += (size_t)N * AGG_F * sizeof(float);
    unsigned short* fbf = (unsigned short*)p;  p += (size_t)N * NODE_F * sizeof(unsigned short);
    int*   deg = (int*)p;              p += (size_t)Np * sizeof(int);
    int*   cur = (int*)p;              p += (size_t)Np * sizeof(int);
    int*   off = (int*)p;              p += (size_t)(Np + 4) * sizeof(int);
    int*   csr = (int*)p;              p += (size_t)E * sizeof(int);
    int*   cutb = (int*)p;             p += (size_t)(G + 1) * sizeof(int);
    int*   bsum = (int*)p;             p += 64 * sizeof(int);

    hipMemsetAsync(deg, 0, (size_t)Np * sizeof(int), stream);

    int eb = (E + 255) / 256;
    k_count<<<eb, 256, 0, stream>>>(edge_dst, deg, E);

    int ng4 = (N + 3) >> 2;
    int nb = (ng4 + 1023) / 1024;
    k_scan_a<<<nb, 1024, 0, stream>>>(deg, off, bsum, N);
    k_scan_b<<<nb, 1024, 0, stream>>>(off, cur, bsum, agg, deg, N, nb);
    k_scatter<<<eb, 256, 0, stream>>>(edge_dst, cur, csr, E);
    k_cut<<<(G + 256) / 256, 256, 0, stream>>>(csr, edge_dst, off, cutb, E, G);

    int ntiles = (N + 15) / 16;
    int gridL = (ntiles + 3) / 4;
    k_node_lin<<<gridL, 256, 0, stream>>>(node_input, node_attr, W1_s, W1_v, fbf, N);

    int gridF = (G + 3) / 4;
    if (gridF > 1536) gridF = 1536;
    k_edge_fused<<<gridF, 256, 0, stream>>>(fbf, edge_scalars, edge_attr, fcW1, fcW2,
                                            edge_src, edge_dst, csr, cutb, agg, E, G);

    int gridO = (ntiles + 3) / 4;
    if (gridO > 640) gridO = 640;
    k_out<<<gridO, 256, 0, stream>>>(node_input, node_attr, agg,
                                     W_sc_s, W_sc_v, W2_s, W2_v, W3, out, N);
}

// Round 14
// 220.750 us; speedup vs baseline: 1.1401x; 1.1401x over previous
//
#include <hip/hip_runtime.h>
#include <math.h>

#define MUL0 64
#define MUL1 32
#define RADF 8
#define HIDF 64
#define WNUM 192
#define NODE_F 160   // 64 + 96
#define AGG_F  384   // A(64) | D(32) | mv_d0(96) | mv_d1(96) | mv_d2(96)

#define INV_SQRT64 0.125f
#define INV_SQRT32 0.17677669529663687f
#define INV_SQRT8  0.35355339059327373f
#define INV_SQRT96 0.10206207261596575f
#define INV_SQRT10 0.31622776601683794f
#define INV_SQRT3  0.5773502691896258f

typedef __attribute__((ext_vector_type(8))) short bf16x8;
typedef __attribute__((ext_vector_type(4))) float f32x4;

__device__ __forceinline__ float bf2f(unsigned short u) {
    return __uint_as_float((unsigned)u << 16);
}
__device__ __forceinline__ unsigned short f2bfu(float x) {
    unsigned ua = __float_as_uint(x);
    return (unsigned short)((ua + 0x7FFF + ((ua >> 16) & 1)) >> 16);
}
__device__ __forceinline__ unsigned bf16pack(float a, float b) {
    unsigned ua = __float_as_uint(a);
    unsigned ub = __float_as_uint(b);
    ua = (ua + 0x7FFF + ((ua >> 16) & 1)) >> 16;
    ub = (ub + 0x7FFF + ((ub >> 16) & 1)) >> 16;
    return ua | (ub << 16);
}
__device__ __forceinline__ int rdlane(int v, int i) {
    return __builtin_amdgcn_readlane(v, i);
}
__device__ __forceinline__ float rdlanef(float v, int i) {
    return __int_as_float(__builtin_amdgcn_readlane(__float_as_int(v), i));
}
__device__ __forceinline__ bf16x8 cvt8(float4 a, float4 b) {
    union { unsigned q[4]; bf16x8 v; } r;
    r.q[0] = bf16pack(a.x, a.y);
    r.q[1] = bf16pack(a.z, a.w);
    r.q[2] = bf16pack(b.x, b.y);
    r.q[3] = bf16pack(b.z, b.w);
    return r.v;
}

// ---------------- kernel: f = _lin(...) via MFMA, wave per 16 nodes, bf16 output ----------------
// f layout (bf16): [n][0:64]=s ; [n][64 + d*32 + u] = v[u][d]
__global__ __launch_bounds__(256) void k_node_lin(
    const float* __restrict__ node_input,
    const float* __restrict__ node_attr,
    const float* __restrict__ W1_s,
    const float* __restrict__ W1_v,
    unsigned short* __restrict__ f, int N)
{
    __shared__ unsigned short s_w1s[8 * 64 * 8];   // 8 KB
    __shared__ unsigned short s_w1v[4 * 32 * 8];   // 2 KB
    int tid = threadIdx.x;

    for (int task = tid; task < 8 * 64; task += 256) {
        int col = task & 63, koct = task >> 6;
        const float* wp = W1_s + (size_t)(koct * 8) * MUL0 + col;
        unsigned pk0 = bf16pack(wp[0 * MUL0] * INV_SQRT64, wp[1 * MUL0] * INV_SQRT64);
        unsigned pk1 = bf16pack(wp[2 * MUL0] * INV_SQRT64, wp[3 * MUL0] * INV_SQRT64);
        unsigned pk2 = bf16pack(wp[4 * MUL0] * INV_SQRT64, wp[5 * MUL0] * INV_SQRT64);
        unsigned pk3 = bf16pack(wp[6 * MUL0] * INV_SQRT64, wp[7 * MUL0] * INV_SQRT64);
        *(uint4*)&s_w1s[task * 8] = make_uint4(pk0, pk1, pk2, pk3);
    }
    for (int task = tid; task < 4 * 32; task += 256) {
        int col = task & 31, koct = task >> 5;
        const float* wp = W1_v + (size_t)(koct * 8) * MUL1 + col;
        unsigned pk0 = bf16pack(wp[0 * MUL1] * INV_SQRT32, wp[1 * MUL1] * INV_SQRT32);
        unsigned pk1 = bf16pack(wp[2 * MUL1] * INV_SQRT32, wp[3 * MUL1] * INV_SQRT32);
        unsigned pk2 = bf16pack(wp[4 * MUL1] * INV_SQRT32, wp[5 * MUL1] * INV_SQRT32);
        unsigned pk3 = bf16pack(wp[6 * MUL1] * INV_SQRT32, wp[7 * MUL1] * INV_SQRT32);
        *(uint4*)&s_w1v[task * 8] = make_uint4(pk0, pk1, pk2, pk3);
    }
    __syncthreads();

    int lane = tid & 63;
    int wv = tid >> 6;
    int l15 = lane & 15, lh = lane >> 4;
    int ntiles = (N + 15) >> 4;

    for (int tile = blockIdx.x * 4 + wv; tile < ntiles; tile += gridDim.x * 4) {
        int n0 = tile << 4;
        int m = min(16, N - n0);
        int nrow = n0 + min(l15, m - 1);
        const float* inn = node_input + (size_t)nrow * NODE_F;

        float attr[4];
        #pragma unroll
        for (int r = 0; r < 4; ++r)
            attr[r] = node_attr[n0 + min(lh * 4 + r, m - 1)];

        bf16x8 inS[2];
        #pragma unroll
        for (int kk = 0; kk < 2; ++kk) {
            const float* p0 = inn + kk * 32 + lh * 8;
            inS[kk] = cvt8(*(const float4*)p0, *(const float4*)(p0 + 4));
        }
        #pragma unroll
        for (int cb = 0; cb < 4; ++cb) {
            f32x4 a = {0.f, 0.f, 0.f, 0.f};
            #pragma unroll
            for (int kk = 0; kk < 2; ++kk) {
                bf16x8 b = *(const bf16x8*)&s_w1s[(((kk * 4 + lh) * 64) + cb * 16 + l15) * 8];
                a = __builtin_amdgcn_mfma_f32_16x16x32_bf16(inS[kk], b, a, 0, 0, 0);
            }
            #pragma unroll
            for (int r = 0; r < 4; ++r) {
                int node = lh * 4 + r;
                if (node < m)
                    f[(size_t)(n0 + node) * NODE_F + cb * 16 + l15] = f2bfu(a[r] * attr[r]);
            }
        }

        #pragma unroll
        for (int d = 0; d < 3; ++d) {
            float t[8];
            #pragma unroll
            for (int j = 0; j < 8; ++j)
                t[j] = inn[64 + (lh * 8 + j) * 3 + d];
            bf16x8 inV = cvt8(make_float4(t[0], t[1], t[2], t[3]),
                              make_float4(t[4], t[5], t[6], t[7]));
            #pragma unroll
            for (int cb = 0; cb < 2; ++cb) {
                bf16x8 b = *(const bf16x8*)&s_w1v[((lh * 32) + cb * 16 + l15) * 8];
                f32x4 a = {0.f, 0.f, 0.f, 0.f};
                a = __builtin_amdgcn_mfma_f32_16x16x32_bf16(inV, b, a, 0, 0, 0);
                #pragma unroll
                for (int r = 0; r < 4; ++r) {
                    int node = lh * 4 + r;
                    if (node < m)
                        f[(size_t)(n0 + node) * NODE_F + 64 + d * 32 + cb * 16 + l15] =
                            f2bfu(a[r] * attr[r]);
                }
            }
        }
    }
}

// ---------------- CSR build ----------------
__global__ void k_count(const int* __restrict__ edge_dst, int* deg, int E)
{
    int e = blockIdx.x * blockDim.x + threadIdx.x;
    if (e < E) atomicAdd(&deg[edge_dst[e]], 1);
}

// multi-block scan: A = per-block local scan + block sums
__global__ __launch_bounds__(1024) void k_scan_a(const int* __restrict__ deg,
                                                 int* __restrict__ off,
                                                 int* __restrict__ bsum, int N)
{
    __shared__ int swsum[16];
    __shared__ int swoff[16];
    __shared__ int stot;
    int lane = threadIdx.x & 63, wid = threadIdx.x >> 6;
    int ng4 = (N + 3) >> 2;
    int g = blockIdx.x * 1024 + threadIdx.x;
    int4 v = make_int4(0, 0, 0, 0);
    if (g < ng4) v = ((const int4*)deg)[g];
    int s = v.x + v.y + v.z + v.w;
    int val = s;
    #pragma unroll
    for (int sh = 1; sh < 64; sh <<= 1) {
        int t = __shfl_up(val, sh);
        if (lane >= sh) val += t;
    }
    if (lane == 63) swsum[wid] = val;
    __syncthreads();
    if (threadIdx.x < 16) {
        int x = swsum[threadIdx.x];
        int xv = x;
        #pragma unroll
        for (int sh = 1; sh < 16; sh <<= 1) {
            int t = __shfl_up(xv, sh);
            if ((int)threadIdx.x >= sh) xv += t;
        }
        swoff[threadIdx.x] = xv - x;
        if (threadIdx.x == 15) stot = xv;
    }
    __syncthreads();
    if (g < ng4) {
        int b0 = swoff[wid] + (val - s);
        int4 o;
        o.x = b0; o.y = b0 + v.x; o.z = o.y + v.y; o.w = o.z + v.z;
        ((int4*)off)[g] = o;
    }
    if (threadIdx.x == 0) bsum[blockIdx.x] = stot;
}

// B: add block bases, write cur
__global__ __launch_bounds__(1024) void k_scan_b(int* __restrict__ off,
                                                 int* __restrict__ cur,
                                                 const int* __restrict__ bsum,
                                                 int N, int nb)
{
    __shared__ int sbase;
    if (threadIdx.x == 0) {
        int s = 0;
        for (int j = 0; j < (int)blockIdx.x; ++j) s += bsum[j];
        sbase = s;
    }
    __syncthreads();
    int base = sbase;
    int ng4 = (N + 3) >> 2;
    int g = blockIdx.x * 1024 + threadIdx.x;
    if (g < ng4) {
        int4 o = ((int4*)off)[g];
        o.x += base; o.y += base; o.z += base; o.w += base;
        ((int4*)off)[g] = o;
        ((int4*)cur)[g] = o;
    }
}

__global__ void k_scatter(const int* __restrict__ edge_dst,
                          int* cur, int* __restrict__ csr, int E)
{
    int e = blockIdx.x * blockDim.x + threadIdx.x;
    if (e < E) {
        int d = edge_dst[e];
        int pos = atomicAdd(&cur[d], 1);
        csr[pos] = e;
    }
}

// ---------------- fused edge kernel: pipelined 16-edge tiles, boundary-aware flush, 8 waves ----------------
#define FLUSH_AGG(node, AT)                                          \
    do {                                                             \
        float* an = agg + (size_t)(node) * AGG_F;                    \
        if (AT) {                                                    \
            atomicAdd(&an[lane], accA);                              \
            atomicAdd(&an[96  + lane], accB0);                       \
            atomicAdd(&an[192 + lane], accB1);                       \
            atomicAdd(&an[288 + lane], accB2);                       \
            if (lane < 32) {                                         \
                atomicAdd(&an[160 + u], accX0);                      \
                atomicAdd(&an[256 + u], accX1);                      \
                atomicAdd(&an[352 + u], accX2);                      \
            } else {                                                 \
                atomicAdd(&an[64 + u], accX0);                       \
            }                                                        \
        } else {                                                     \
            an[lane] = accA;                                         \
            an[96  + lane] = accB0;                                  \
            an[192 + lane] = accB1;                                  \
            an[288 + lane] = accB2;                                  \
            if (lane < 32) {                                         \
                an[160 + u] = accX0;                                 \
                an[256 + u] = accX1;                                 \
                an[352 + u] = accX2;                                 \
            } else {                                                 \
                an[64 + u] = accX0;                                  \
            }                                                        \
        }                                                            \
    } while (0)

__global__ __launch_bounds__(512, 2) void k_edge_fused(
    const unsigned short* __restrict__ f,
    const float* __restrict__ edge_scalars,
    const float* __restrict__ edge_attr,
    const float* __restrict__ fcW1,
    const float* __restrict__ fcW2,
    const int* __restrict__ edge_src,
    const int* __restrict__ edge_dst,
    const int* __restrict__ csr,
    const int* __restrict__ off,
    float* agg, int E)
{
    __shared__ unsigned short s_w2t[8 * 192 * 8];   // 24576 B
    __shared__ unsigned short s_w[8][16 * 216];     // 55296 B
    __shared__ float s_fcW1[512];                   //  2048 B  -> 81920 B = 80 KB

    int tid  = threadIdx.x;
    int lane = tid & 63;
    int wv   = tid >> 6;                 // 0..7
    int l15  = lane & 15, lh = lane >> 4;
    int u    = lane & 31;

    for (int task = tid; task < 1536; task += 512) {
        int col = task % 192, oct = task / 192;
        const float* wp = fcW2 + (size_t)(oct * 8) * WNUM + col;
        unsigned pk0 = bf16pack(wp[0 * WNUM], wp[1 * WNUM]);
        unsigned pk1 = bf16pack(wp[2 * WNUM], wp[3 * WNUM]);
        unsigned pk2 = bf16pack(wp[4 * WNUM], wp[5 * WNUM]);
        unsigned pk3 = bf16pack(wp[6 * WNUM], wp[7 * WNUM]);
        *(uint4*)&s_w2t[oct * 1536 + col * 8] = make_uint4(pk0, pk1, pk2, pk3);
    }
    for (int i = tid; i < 512; i += 512)
        s_fcW1[i] = fcW1[i];
    __syncthreads();      // the only block barrier

    unsigned short* sw = s_w[wv];
    int nwt = (E + 15) >> 4;
    int stride8 = gridDim.x * 8;

    int wt = blockIdx.x * 8 + wv;
    if (wt >= nwt) return;

    // ---- prologue: metadata chain for first tile ----
    int P = wt << 4;
    int m = min(16, E - P);
    int e0 = csr[P + min(l15, m - 1)];
    int src = edge_src[e0];
    int dst = edge_dst[e0];
    float4 ea = *(const float4*)(edge_attr + (size_t)e0 * 4);
    float4 es0, es1;
    {
        const float4* esp = (const float4*)(edge_scalars + (size_t)e0 * RADF);
        es0 = esp[0]; es1 = esp[1];
    }

    while (true) {
        // ---- segment-boundary info (wave-uniform scalar loads) ----
        int firstd = rdlane(dst, 0);
        int lastd  = rdlane(dst, m - 1);
        int off_first = off[firstd];
        int off_last  = off[lastd + 1];

        int wt_n = wt + stride8;
        bool hn = wt_n < nwt;
        int P_n = hn ? (wt_n << 4) : 0;
        int m_n = hn ? min(16, E - P_n) : 1;

        // ---- issue next-tile csr FIRST ----
        int e_n = csr[hn ? (P_n + min(l15, m_n - 1)) : 0];

        // ---- issue current-tile f gather (bf16, 64 loads) ----
        float xs[16], xv0[16], xv1[16], xv2[16];
        #pragma unroll
        for (int i = 0; i < 16; ++i) {
            int si = rdlane(src, i);
            const unsigned short* fb = f + (size_t)si * NODE_F;
            xs[i]  = bf2f(fb[lane]);
            xv0[i] = bf2f(fb[64 + u]);
            xv1[i] = bf2f(fb[96 + u]);
            xv2[i] = bf2f(fb[128 + u]);
        }

        // ---- h compute (registers only; covers csr latency) ----
        float es[8] = {es0.x, es0.y, es0.z, es0.w, es1.x, es1.y, es1.z, es1.w};
        union { unsigned q[4]; bf16x8 v; } A0, A1;
        #pragma unroll
        for (int jp = 0; jp < 4; ++jp) {
            int k0 = lh * 8 + 2 * jp;
            float aL0 = 0.f, aL1 = 0.f, aH0 = 0.f, aH1 = 0.f;
            #pragma unroll
            for (int r = 0; r < 8; ++r) {
                float2 wl = *(const float2*)&s_fcW1[r * 64 + k0];
                float2 wh = *(const float2*)&s_fcW1[r * 64 + 32 + k0];
                aL0 = fmaf(es[r], wl.x, aL0);
                aL1 = fmaf(es[r], wl.y, aL1);
                aH0 = fmaf(es[r], wh.x, aH0);
                aH1 = fmaf(es[r], wh.y, aH1);
            }
            aL0 *= INV_SQRT8; aL1 *= INV_SQRT8; aH0 *= INV_SQRT8; aH1 *= INV_SQRT8;
            aL0 = aL0 / (1.f + __expf(-aL0));
            aL1 = aL1 / (1.f + __expf(-aL1));
            aH0 = aH0 / (1.f + __expf(-aH0));
            aH1 = aH1 / (1.f + __expf(-aH1));
            A0.q[jp] = bf16pack(aL0, aL1);
            A1.q[jp] = bf16pack(aH0, aH1);
        }

        // ---- issue next-tile metadata ----
        int src_n = edge_src[e_n];
        int dst_n = edge_dst[e_n];
        float4 ea_n = *(const float4*)(edge_attr + (size_t)e_n * 4);
        float4 es0_n, es1_n;
        {
            const float4* espn = (const float4*)(edge_scalars + (size_t)e_n * RADF);
            es0_n = espn[0]; es1_n = espn[1];
        }

        // ---- MFMA: w = h @ fcW2 / sqrt(64) ----
        #pragma unroll
        for (int cb = 0; cb < 12; ++cb) {
            bf16x8 b0 = *(const bf16x8*)&s_w2t[ lh      * 1536 + (cb * 16 + l15) * 8];
            bf16x8 b1 = *(const bf16x8*)&s_w2t[(4 + lh) * 1536 + (cb * 16 + l15) * 8];
            f32x4 acc = {0.f, 0.f, 0.f, 0.f};
            acc = __builtin_amdgcn_mfma_f32_16x16x32_bf16(A0.v, b0, acc, 0, 0, 0);
            acc = __builtin_amdgcn_mfma_f32_16x16x32_bf16(A1.v, b1, acc, 0, 0, 0);
            #pragma unroll
            for (int r = 0; r < 4; ++r)
                sw[(lh * 4 + r) * 216 + cb * 16 + l15] = f2bfu(acc[r] * INV_SQRT64);
        }

        // ---- TP + dst-segmented reduction (plain store if segment contained) ----
        float accA = 0.f, accB0 = 0.f, accB1 = 0.f, accB2 = 0.f;
        float accX0 = 0.f, accX1 = 0.f, accX2 = 0.f;
        int curd = rdlane(dst, 0);
        #pragma unroll
        for (int i = 0; i < 16; ++i) {
            if (i < m) {
                int di = rdlane(dst, i);
                if (di != curd) {
                    bool at = (curd == firstd) && (off_first < P);
                    FLUSH_AGG(curd, at);
                    accA = accB0 = accB1 = accB2 = 0.f;
                    accX0 = accX1 = accX2 = 0.f;
                    curd = di;
                }
                float eax = rdlanef(ea.x, i);
                float eay = rdlanef(ea.y, i);
                float eaz = rdlanef(ea.z, i);
                float eaw = rdlanef(ea.w, i);
                float W0 = bf2f(sw[i * 216 + lane]);
                float W1 = bf2f(sw[i * 216 + 64 + lane]);
                float W2 = bf2f(sw[i * 216 + 128 + lane]);
                accA = fmaf(W0 * xs[i], eax, accA);
                float bx = W1 * xs[i];
                accB0 = fmaf(bx, eay, accB0);
                accB1 = fmaf(bx, eaz, accB1);
                accB2 = fmaf(bx, eaw, accB2);
                if (lane < 32) {
                    float cc = W2 * eax;
                    accX0 = fmaf(cc, xv0[i], accX0);
                    accX1 = fmaf(cc, xv1[i], accX1);
                    accX2 = fmaf(cc, xv2[i], accX2);
                } else {
                    float dv = xv0[i] * eay + xv1[i] * eaz + xv2[i] * eaw;
                    accX0 = fmaf(W2 * INV_SQRT3, dv, accX0);
                }
            }
        }
        {
            bool at_fin = ((curd == firstd) && (off_first < P)) || (off_last > P + m);
            FLUSH_AGG(curd, at_fin);
        }

        if (!hn) break;
        wt = wt_n; P = P_n; m = m_n;
        src = src_n; dst = dst_n; ea = ea_n; es0 = es0_n; es1 = es1_n;
    }
}

// ---------------- kernel: output combine via MFMA, wave per 16 nodes ----------------
__global__ __launch_bounds__(256) void k_out(
    const float* __restrict__ node_input,
    const float* __restrict__ node_attr,
    const float* __restrict__ agg,
    const float* __restrict__ W_sc_s,
    const float* __restrict__ W_sc_v,
    const float* __restrict__ W2_s,
    const float* __restrict__ W2_v,
    const float* __restrict__ W3,
    float* __restrict__ out, int N)
{
    __shared__ unsigned short s_w2s[12 * 64 * 8];   // 12288 B
    __shared__ unsigned short s_wss[ 8 * 64 * 8];   //  8192 B
    __shared__ unsigned short s_w2v[12 * 32 * 8];   //  6144 B
    __shared__ unsigned short s_wsv[ 4 * 32 * 8];   //  2048 B
    __shared__ unsigned short s_w3 [12 * 16 * 8];   //  3072 B  -> 31744 B total

    const float pre = INV_SQRT10 * INV_SQRT96;
    int tid = threadIdx.x;

    for (int task = tid; task < 12 * 64; task += 256) {         // W2_s
        int col = task & 63, koct = task >> 6;
        const float* wp = W2_s + (size_t)(koct * 8) * MUL0 + col;
        unsigned pk0 = bf16pack(wp[0 * MUL0] * pre, wp[1 * MUL0] * pre);
        unsigned pk1 = bf16pack(wp[2 * MUL0] * pre, wp[3 * MUL0] * pre);
        unsigned pk2 = bf16pack(wp[4 * MUL0] * pre, wp[5 * MUL0] * pre);
        unsigned pk3 = bf16pack(wp[6 * MUL0] * pre, wp[7 * MUL0] * pre);
        *(uint4*)&s_w2s[task * 8] = make_uint4(pk0, pk1, pk2, pk3);
    }
    for (int task = tid; task < 8 * 64; task += 256) {          // W_sc_s
        int col = task & 63, koct = task >> 6;
        const float* wp = W_sc_s + (size_t)(koct * 8) * MUL0 + col;
        unsigned pk0 = bf16pack(wp[0 * MUL0] * INV_SQRT64, wp[1 * MUL0] * INV_SQRT64);
        unsigned pk1 = bf16pack(wp[2 * MUL0] * INV_SQRT64, wp[3 * MUL0] * INV_SQRT64);
        unsigned pk2 = bf16pack(wp[4 * MUL0] * INV_SQRT64, wp[5 * MUL0] * INV_SQRT64);
        unsigned pk3 = bf16pack(wp[6 * MUL0] * INV_SQRT64, wp[7 * MUL0] * INV_SQRT64);
        *(uint4*)&s_wss[task * 8] = make_uint4(pk0, pk1, pk2, pk3);
    }
    for (int task = tid; task < 12 * 32; task += 256) {         // W2_v
        int col = task & 31, koct = task >> 5;
        const float* wp = W2_v + (size_t)(koct * 8) * MUL1 + col;
        unsigned pk0 = bf16pack(wp[0 * MUL1] * pre, wp[1 * MUL1] * pre);
        unsigned pk1 = bf16pack(wp[2 * MUL1] * pre, wp[3 * MUL1] * pre);
        unsigned pk2 = bf16pack(wp[4 * MUL1] * pre, wp[5 * MUL1] * pre);
        unsigned pk3 = bf16pack(wp[6 * MUL1] * pre, wp[7 * MUL1] * pre);
        *(uint4*)&s_w2v[task * 8] = make_uint4(pk0, pk1, pk2, pk3);
    }
    for (int task = tid; task < 4 * 32; task += 256) {          // W_sc_v
        int col = task & 31, koct = task >> 5;
        const float* wp = W_sc_v + (size_t)(koct * 8) * MUL1 + col;
        unsigned pk0 = bf16pack(wp[0 * MUL1] * INV_SQRT32, wp[1 * MUL1] * INV_SQRT32);
        unsigned pk1 = bf16pack(wp[2 * MUL1] * INV_SQRT32, wp[3 * MUL1] * INV_SQRT32);
        unsigned pk2 = bf16pack(wp[4 * MUL1] * INV_SQRT32, wp[5 * MUL1] * INV_SQRT32);
        unsigned pk3 = bf16pack(wp[6 * MUL1] * INV_SQRT32, wp[7 * MUL1] * INV_SQRT32);
        *(uint4*)&s_wsv[task * 8] = make_uint4(pk0, pk1, pk2, pk3);
    }
    for (int task = tid; task < 12 * 16; task += 256) {         // W3 block
        int col = task & 15, koct = task >> 4;
        const float sc3 = 0.1f * pre;
        unsigned pk0 = 0, pk1 = 0, pk2 = 0, pk3 = 0;
        if (col == 0) {
            const float* wp = W3 + koct * 8;
            pk0 = bf16pack(wp[0] * sc3, wp[1] * sc3);
            pk1 = bf16pack(wp[2] * sc3, wp[3] * sc3);
            pk2 = bf16pack(wp[4] * sc3, wp[5] * sc3);
            pk3 = bf16pack(wp[6] * sc3, wp[7] * sc3);
        }
        *(uint4*)&s_w3[task * 8] = make_uint4(pk0, pk1, pk2, pk3);
    }
    __syncthreads();

    int lane = tid & 63;
    int wv = tid >> 6;
    int l15 = lane & 15, lh = lane >> 4;
    int ntiles = (N + 15) >> 4;

    for (int tile = blockIdx.x * 4 + wv; tile < ntiles; tile += gridDim.x * 4) {
        int n0 = tile << 4;
        int m = min(16, N - n0);
        int nrow = n0 + min(l15, m - 1);
        const float* agn = agg + (size_t)nrow * AGG_F;
        const float* inn = node_input + (size_t)nrow * NODE_F;

        bf16x8 aggA[3], inS[2];
        #pragma unroll
        for (int kk = 0; kk < 3; ++kk) {
            const float* p0 = agn + kk * 32 + lh * 8;
            aggA[kk] = cvt8(*(const float4*)p0, *(const float4*)(p0 + 4));
        }
        #pragma unroll
        for (int kk = 0; kk < 2; ++kk) {
            const float* p0 = inn + kk * 32 + lh * 8;
            inS[kk] = cvt8(*(const float4*)p0, *(const float4*)(p0 + 4));
        }

        f32x4 convS[4], scS[4], angD = {0.f, 0.f, 0.f, 0.f};
        #pragma unroll
        for (int cb = 0; cb < 4; ++cb) {
            f32x4 a = {0.f, 0.f, 0.f, 0.f};
            #pragma unroll
            for (int kk = 0; kk < 3; ++kk) {
                bf16x8 b = *(const bf16x8*)&s_w2s[(((kk * 4 + lh) * 64) + cb * 16 + l15) * 8];
                a = __builtin_amdgcn_mfma_f32_16x16x32_bf16(aggA[kk], b, a, 0, 0, 0);
            }
            convS[cb] = a;
            f32x4 s = {0.f, 0.f, 0.f, 0.f};
            #pragma unroll
            for (int kk = 0; kk < 2; ++kk) {
                bf16x8 b = *(const bf16x8*)&s_wss[(((kk * 4 + lh) * 64) + cb * 16 + l15) * 8];
                s = __builtin_amdgcn_mfma_f32_16x16x32_bf16(inS[kk], b, s, 0, 0, 0);
            }
            scS[cb] = s;
        }
        #pragma unroll
        for (int kk = 0; kk < 3; ++kk) {
            bf16x8 b = *(const bf16x8*)&s_w3[(((kk * 4 + lh) * 16) + l15) * 8];
            angD = __builtin_amdgcn_mfma_f32_16x16x32_bf16(aggA[kk], b, angD, 0, 0, 0);
        }

        float attr[4], cs[4], sn[4];
        #pragma unroll
        for (int r = 0; r < 4; ++r) {
            attr[r] = node_attr[n0 + min(lh * 4 + r, m - 1)];
            float ang = __shfl(angD[r], lane & 48) * attr[r];
            cs[r] = cosf(ang);
            sn[r] = sinf(ang);
        }

        #pragma unroll
        for (int cb = 0; cb < 4; ++cb)
            #pragma unroll
            for (int r = 0; r < 4; ++r) {
                int node = lh * 4 + r;
                if (node < m)
                    out[(size_t)(n0 + node) * NODE_F + cb * 16 + l15] =
                        attr[r] * (cs[r] * scS[cb][r] + sn[r] * convS[cb][r]);
            }

        #pragma unroll
        for (int d = 0; d < 3; ++d) {
            bf16x8 aggV[3], inV;
            #pragma unroll
            for (int kk = 0; kk < 3; ++kk) {
                const float* p0 = agn + 96 + d * 96 + kk * 32 + lh * 8;
                aggV[kk] = cvt8(*(const float4*)p0, *(const float4*)(p0 + 4));
            }
            {
                float t[8];
                #pragma unroll
                for (int j = 0; j < 8; ++j)
                    t[j] = inn[64 + (lh * 8 + j) * 3 + d];
                inV = cvt8(make_float4(t[0], t[1], t[2], t[3]),
                           make_float4(t[4], t[5], t[6], t[7]));
            }
            #pragma unroll
            for (int cb = 0; cb < 2; ++cb) {
                f32x4 a = {0.f, 0.f, 0.f, 0.f};
                #pragma unroll
                for (int kk = 0; kk < 3; ++kk) {
                    bf16x8 b = *(const bf16x8*)&s_w2v[(((kk * 4 + lh) * 32) + cb * 16 + l15) * 8];
                    a = __builtin_amdgcn_mfma_f32_16x16x32_bf16(aggV[kk], b, a, 0, 0, 0);
                }
                f32x4 s = {0.f, 0.f, 0.f, 0.f};
                {
                    bf16x8 b = *(const bf16x8*)&s_wsv[((lh * 32) + cb * 16 + l15) * 8];
                    s = __builtin_amdgcn_mfma_f32_16x16x32_bf16(inV, b, s, 0, 0, 0);
                }
                #pragma unroll
                for (int r = 0; r < 4; ++r) {
                    int node = lh * 4 + r;
                    if (node < m)
                        out[(size_t)(n0 + node) * NODE_F + 64 + (cb * 16 + l15) * 3 + d] =
                            attr[r] * (cs[r] * s[r] + sn[r] * a[r]);
                }
            }
        }
    }
}

extern "C" void kernel_launch(void* const* d_in, const int* in_sizes, int n_in,
                              void* d_out, int out_size, void* d_ws, size_t ws_size,
                              hipStream_t stream)
{
    const float* node_input   = (const float*)d_in[0];
    const float* node_attr    = (const float*)d_in[1];
    const float* edge_attr    = (const float*)d_in[2];
    const float* edge_scalars = (const float*)d_in[3];
    const float* W_sc_s       = (const float*)d_in[4];
    const float* W_sc_v       = (const float*)d_in[5];
    const float* W1_s         = (const float*)d_in[6];
    const float* W1_v         = (const float*)d_in[7];
    const float* W2_s         = (const float*)d_in[8];
    const float* W2_v         = (const float*)d_in[9];
    const float* W3           = (const float*)d_in[10];
    const float* fcW1         = (const float*)d_in[11];
    const float* fcW2         = (const float*)d_in[12];
    const int*   edge_src     = (const int*)d_in[13];
    const int*   edge_dst     = (const int*)d_in[14];
    float* out = (float*)d_out;

    const int N = in_sizes[1];
    const int E = in_sizes[13];
    const int Np = (N + 3) & ~3;          // pad for int4 scan

    // ---- workspace layout ----
    char* p = (char*)d_ws;
    float* agg = (float*)p;            p += (size_t)N * AGG_F * sizeof(float);
    unsigned short* fbf = (unsigned short*)p;  p += (size_t)N * NODE_F * sizeof(unsigned short);
    int*   deg = (int*)p;              p += (size_t)Np * sizeof(int);
    int*   cur = (int*)p;              p += (size_t)Np * sizeof(int);
    int*   off = (int*)p;              p += (size_t)(Np + 4) * sizeof(int);
    int*   csr = (int*)p;              p += (size_t)E * sizeof(int);
    int*   bsum = (int*)p;             p += 64 * sizeof(int);

    hipMemsetAsync(deg, 0, (size_t)Np * sizeof(int), stream);
    hipMemsetAsync(agg, 0, (size_t)N * AGG_F * sizeof(float), stream);

    int eb = (E + 255) / 256;
    k_count<<<eb, 256, 0, stream>>>(edge_dst, deg, E);

    int ng4 = (N + 3) >> 2;
    int nb = (ng4 + 1023) / 1024;
    k_scan_a<<<nb, 1024, 0, stream>>>(deg, off, bsum, N);
    k_scan_b<<<nb, 1024, 0, stream>>>(off, cur, bsum, N, nb);
    k_scatter<<<eb, 256, 0, stream>>>(edge_dst, cur, csr, E);

    int ntiles = (N + 15) / 16;
    int gridL = (ntiles + 3) / 4;
    k_node_lin<<<gridL, 256, 0, stream>>>(node_input, node_attr, W1_s, W1_v, fbf, N);

    int nwt = (E + 15) / 16;
    int gridF = (nwt + 7) / 8;
    if (gridF > 1024) gridF = 1024;
    k_edge_fused<<<gridF, 512, 0, stream>>>(fbf, edge_scalars, edge_attr, fcW1, fcW2,
                                            edge_src, edge_dst, csr, off, agg, E);

    int gridO = (ntiles + 3) / 4;
    if (gridO > 640) gridO = 640;
    k_out<<<gridO, 256, 0, stream>>>(node_input, node_attr, agg,
                                     W_sc_s, W_sc_v, W2_s, W2_v, W3, out, N);
}

// Round 15
// 220.372 us; speedup vs baseline: 1.1421x; 1.0017x over previous
//
#include <hip/hip_runtime.h>
#include <math.h>

#define MUL0 64
#define MUL1 32
#define RADF 8
#define HIDF 64
#define WNUM 192
#define NODE_F 160   // 64 + 96
#define AGG_F  384   // A(64) | D(32) | mv_d0(96) | mv_d1(96) | mv_d2(96)
#define SWS 200      // s_w row stride (shorts)

#define INV_SQRT64 0.125f
#define INV_SQRT32 0.17677669529663687f
#define INV_SQRT8  0.35355339059327373f
#define INV_SQRT96 0.10206207261596575f
#define INV_SQRT10 0.31622776601683794f
#define INV_SQRT3  0.5773502691896258f

typedef __attribute__((ext_vector_type(8))) short bf16x8;
typedef __attribute__((ext_vector_type(4))) float f32x4;

__device__ __forceinline__ float bf2f(unsigned short u) {
    return __uint_as_float((unsigned)u << 16);
}
__device__ __forceinline__ unsigned short f2bfu(float x) {
    unsigned ua = __float_as_uint(x);
    return (unsigned short)((ua + 0x7FFF + ((ua >> 16) & 1)) >> 16);
}
__device__ __forceinline__ unsigned bf16pack(float a, float b) {
    unsigned ua = __float_as_uint(a);
    unsigned ub = __float_as_uint(b);
    ua = (ua + 0x7FFF + ((ua >> 16) & 1)) >> 16;
    ub = (ub + 0x7FFF + ((ub >> 16) & 1)) >> 16;
    return ua | (ub << 16);
}
__device__ __forceinline__ int rdlane(int v, int i) {
    return __builtin_amdgcn_readlane(v, i);
}
__device__ __forceinline__ float rdlanef(float v, int i) {
    return __int_as_float(__builtin_amdgcn_readlane(__float_as_int(v), i));
}
__device__ __forceinline__ bf16x8 cvt8(float4 a, float4 b) {
    union { unsigned q[4]; bf16x8 v; } r;
    r.q[0] = bf16pack(a.x, a.y);
    r.q[1] = bf16pack(a.z, a.w);
    r.q[2] = bf16pack(b.x, b.y);
    r.q[3] = bf16pack(b.z, b.w);
    return r.v;
}

// ---------------- kernel: f = _lin(...) via MFMA, wave per 16 nodes, bf16 output ----------------
// f layout (bf16): [n][0:64]=s ; [n][64 + d*32 + u] = v[u][d]
__global__ __launch_bounds__(256) void k_node_lin(
    const float* __restrict__ node_input,
    const float* __restrict__ node_attr,
    const float* __restrict__ W1_s,
    const float* __restrict__ W1_v,
    unsigned short* __restrict__ f, int N)
{
    __shared__ unsigned short s_w1s[8 * 64 * 8];   // 8 KB
    __shared__ unsigned short s_w1v[4 * 32 * 8];   // 2 KB
    int tid = threadIdx.x;

    for (int task = tid; task < 8 * 64; task += 256) {
        int col = task & 63, koct = task >> 6;
        const float* wp = W1_s + (size_t)(koct * 8) * MUL0 + col;
        unsigned pk0 = bf16pack(wp[0 * MUL0] * INV_SQRT64, wp[1 * MUL0] * INV_SQRT64);
        unsigned pk1 = bf16pack(wp[2 * MUL0] * INV_SQRT64, wp[3 * MUL0] * INV_SQRT64);
        unsigned pk2 = bf16pack(wp[4 * MUL0] * INV_SQRT64, wp[5 * MUL0] * INV_SQRT64);
        unsigned pk3 = bf16pack(wp[6 * MUL0] * INV_SQRT64, wp[7 * MUL0] * INV_SQRT64);
        *(uint4*)&s_w1s[task * 8] = make_uint4(pk0, pk1, pk2, pk3);
    }
    for (int task = tid; task < 4 * 32; task += 256) {
        int col = task & 31, koct = task >> 5;
        const float* wp = W1_v + (size_t)(koct * 8) * MUL1 + col;
        unsigned pk0 = bf16pack(wp[0 * MUL1] * INV_SQRT32, wp[1 * MUL1] * INV_SQRT32);
        unsigned pk1 = bf16pack(wp[2 * MUL1] * INV_SQRT32, wp[3 * MUL1] * INV_SQRT32);
        unsigned pk2 = bf16pack(wp[4 * MUL1] * INV_SQRT32, wp[5 * MUL1] * INV_SQRT32);
        unsigned pk3 = bf16pack(wp[6 * MUL1] * INV_SQRT32, wp[7 * MUL1] * INV_SQRT32);
        *(uint4*)&s_w1v[task * 8] = make_uint4(pk0, pk1, pk2, pk3);
    }
    __syncthreads();

    int lane = tid & 63;
    int wv = tid >> 6;
    int l15 = lane & 15, lh = lane >> 4;
    int ntiles = (N + 15) >> 4;

    for (int tile = blockIdx.x * 4 + wv; tile < ntiles; tile += gridDim.x * 4) {
        int n0 = tile << 4;
        int m = min(16, N - n0);
        int nrow = n0 + min(l15, m - 1);
        const float* inn = node_input + (size_t)nrow * NODE_F;

        float attr[4];
        #pragma unroll
        for (int r = 0; r < 4; ++r)
            attr[r] = node_attr[n0 + min(lh * 4 + r, m - 1)];

        bf16x8 inS[2];
        #pragma unroll
        for (int kk = 0; kk < 2; ++kk) {
            const float* p0 = inn + kk * 32 + lh * 8;
            inS[kk] = cvt8(*(const float4*)p0, *(const float4*)(p0 + 4));
        }
        #pragma unroll
        for (int cb = 0; cb < 4; ++cb) {
            f32x4 a = {0.f, 0.f, 0.f, 0.f};
            #pragma unroll
            for (int kk = 0; kk < 2; ++kk) {
                bf16x8 b = *(const bf16x8*)&s_w1s[(((kk * 4 + lh) * 64) + cb * 16 + l15) * 8];
                a = __builtin_amdgcn_mfma_f32_16x16x32_bf16(inS[kk], b, a, 0, 0, 0);
            }
            #pragma unroll
            for (int r = 0; r < 4; ++r) {
                int node = lh * 4 + r;
                if (node < m)
                    f[(size_t)(n0 + node) * NODE_F + cb * 16 + l15] = f2bfu(a[r] * attr[r]);
            }
        }

        #pragma unroll
        for (int d = 0; d < 3; ++d) {
            float t[8];
            #pragma unroll
            for (int j = 0; j < 8; ++j)
                t[j] = inn[64 + (lh * 8 + j) * 3 + d];
            bf16x8 inV = cvt8(make_float4(t[0], t[1], t[2], t[3]),
                              make_float4(t[4], t[5], t[6], t[7]));
            #pragma unroll
            for (int cb = 0; cb < 2; ++cb) {
                bf16x8 b = *(const bf16x8*)&s_w1v[((lh * 32) + cb * 16 + l15) * 8];
                f32x4 a = {0.f, 0.f, 0.f, 0.f};
                a = __builtin_amdgcn_mfma_f32_16x16x32_bf16(inV, b, a, 0, 0, 0);
                #pragma unroll
                for (int r = 0; r < 4; ++r) {
                    int node = lh * 4 + r;
                    if (node < m)
                        f[(size_t)(n0 + node) * NODE_F + 64 + d * 32 + cb * 16 + l15] =
                            f2bfu(a[r] * attr[r]);
                }
            }
        }
    }
}

// ---------------- CSR build ----------------
__global__ void k_count(const int* __restrict__ edge_dst, int* deg, int E)
{
    int e = blockIdx.x * blockDim.x + threadIdx.x;
    if (e < E) atomicAdd(&deg[edge_dst[e]], 1);
}

// multi-block scan: A = per-block local scan + block sums
__global__ __launch_bounds__(1024) void k_scan_a(const int* __restrict__ deg,
                                                 int* __restrict__ off,
                                                 int* __restrict__ bsum, int N)
{
    __shared__ int swsum[16];
    __shared__ int swoff[16];
    __shared__ int stot;
    int lane = threadIdx.x & 63, wid = threadIdx.x >> 6;
    int ng4 = (N + 3) >> 2;
    int g = blockIdx.x * 1024 + threadIdx.x;
    int4 v = make_int4(0, 0, 0, 0);
    if (g < ng4) v = ((const int4*)deg)[g];
    int s = v.x + v.y + v.z + v.w;
    int val = s;
    #pragma unroll
    for (int sh = 1; sh < 64; sh <<= 1) {
        int t = __shfl_up(val, sh);
        if (lane >= sh) val += t;
    }
    if (lane == 63) swsum[wid] = val;
    __syncthreads();
    if (threadIdx.x < 16) {
        int x = swsum[threadIdx.x];
        int xv = x;
        #pragma unroll
        for (int sh = 1; sh < 16; sh <<= 1) {
            int t = __shfl_up(xv, sh);
            if ((int)threadIdx.x >= sh) xv += t;
        }
        swoff[threadIdx.x] = xv - x;
        if (threadIdx.x == 15) stot = xv;
    }
    __syncthreads();
    if (g < ng4) {
        int b0 = swoff[wid] + (val - s);
        int4 o;
        o.x = b0; o.y = b0 + v.x; o.z = o.y + v.y; o.w = o.z + v.z;
        ((int4*)off)[g] = o;
    }
    if (threadIdx.x == 0) bsum[blockIdx.x] = stot;
}

// B: add block bases, write cur
__global__ __launch_bounds__(1024) void k_scan_b(int* __restrict__ off,
                                                 int* __restrict__ cur,
                                                 const int* __restrict__ bsum,
                                                 int N, int nb)
{
    __shared__ int sbase;
    if (threadIdx.x == 0) {
        int s = 0;
        for (int j = 0; j < (int)blockIdx.x; ++j) s += bsum[j];
        sbase = s;
    }
    __syncthreads();
    int base = sbase;
    int ng4 = (N + 3) >> 2;
    int g = blockIdx.x * 1024 + threadIdx.x;
    if (g < ng4) {
        int4 o = ((int4*)off)[g];
        o.x += base; o.y += base; o.z += base; o.w += base;
        ((int4*)off)[g] = o;
        ((int4*)cur)[g] = o;
    }
}

__global__ void k_scatter(const int* __restrict__ edge_dst,
                          int* cur, int* __restrict__ csr, int E)
{
    int e = blockIdx.x * blockDim.x + threadIdx.x;
    if (e < E) {
        int d = edge_dst[e];
        int pos = atomicAdd(&cur[d], 1);
        csr[pos] = e;
    }
}

// ---------------- fused edge kernel: pipelined 16-edge tiles, boundary-aware flush, 8 waves ----------------
#define FLUSH_AGG(node, AT)                                          \
    do {                                                             \
        float* an = agg + (size_t)(node) * AGG_F;                    \
        if (AT) {                                                    \
            atomicAdd(&an[lane], accA);                              \
            atomicAdd(&an[96  + lane], accB0);                       \
            atomicAdd(&an[192 + lane], accB1);                       \
            atomicAdd(&an[288 + lane], accB2);                       \
            if (lane < 32) {                                         \
                atomicAdd(&an[160 + u], accX0);                      \
                atomicAdd(&an[256 + u], accX1);                      \
                atomicAdd(&an[352 + u], accX2);                      \
            } else {                                                 \
                atomicAdd(&an[64 + u], accX0);                       \
            }                                                        \
        } else {                                                     \
            an[lane] = accA;                                         \
            an[96  + lane] = accB0;                                  \
            an[192 + lane] = accB1;                                  \
            an[288 + lane] = accB2;                                  \
            if (lane < 32) {                                         \
                an[160 + u] = accX0;                                 \
                an[256 + u] = accX1;                                 \
                an[352 + u] = accX2;                                 \
            } else {                                                 \
                an[64 + u] = accX0;                                  \
            }                                                        \
        }                                                            \
    } while (0)

__global__ __launch_bounds__(512, 2) void k_edge_fused(
    const unsigned short* __restrict__ f,
    const float* __restrict__ edge_scalars,
    const float* __restrict__ edge_attr,
    const float* __restrict__ fcW1,
    const float* __restrict__ fcW2,
    const int* __restrict__ edge_src,
    const int* __restrict__ edge_dst,
    const int* __restrict__ csr,
    const int* __restrict__ off,
    float* agg, int E)
{
    __shared__ unsigned short s_w2t[8 * 192 * 8];   // 24576 B
    __shared__ unsigned short s_w[8][16 * SWS];     // 51200 B
    __shared__ float s_fcW1[512];                   //  2048 B
    __shared__ float4 s_ea8[8][16];                 //  2048 B  -> 79872 B total

    int tid  = threadIdx.x;
    int lane = tid & 63;
    int wv   = tid >> 6;                 // 0..7
    int l15  = lane & 15, lh = lane >> 4;
    int u    = lane & 31;

    for (int task = tid; task < 1536; task += 512) {
        int col = task % 192, oct = task / 192;
        const float* wp = fcW2 + (size_t)(oct * 8) * WNUM + col;
        unsigned pk0 = bf16pack(wp[0 * WNUM], wp[1 * WNUM]);
        unsigned pk1 = bf16pack(wp[2 * WNUM], wp[3 * WNUM]);
        unsigned pk2 = bf16pack(wp[4 * WNUM], wp[5 * WNUM]);
        unsigned pk3 = bf16pack(wp[6 * WNUM], wp[7 * WNUM]);
        *(uint4*)&s_w2t[oct * 1536 + col * 8] = make_uint4(pk0, pk1, pk2, pk3);
    }
    for (int i = tid; i < 512; i += 512)
        s_fcW1[i] = fcW1[i];
    __syncthreads();      // the only block barrier

    unsigned short* sw = s_w[wv];
    float4* sea = s_ea8[wv];
    int nwt = (E + 15) >> 4;
    int stride8 = gridDim.x * 8;

    int wt = blockIdx.x * 8 + wv;
    if (wt >= nwt) return;

    // ---- prologue: metadata chain for first tile ----
    int P = wt << 4;
    int m = min(16, E - P);
    int e0 = csr[P + min(l15, m - 1)];
    int src = edge_src[e0];
    int dst = edge_dst[e0];
    float4 ea = *(const float4*)(edge_attr + (size_t)e0 * 4);
    float4 es0, es1;
    {
        const float4* esp = (const float4*)(edge_scalars + (size_t)e0 * RADF);
        es0 = esp[0]; es1 = esp[1];
    }

    while (true) {
        // ---- per-wave ea table (replaces 64 readlanes with 16 broadcast LDS reads) ----
        if (lh == 0) sea[l15] = ea;

        // ---- segment-boundary info (wave-uniform scalar loads) ----
        int firstd = rdlane(dst, 0);
        int lastd  = rdlane(dst, m - 1);
        int off_first = off[firstd];
        int off_last  = off[lastd + 1];

        int wt_n = wt + stride8;
        bool hn = wt_n < nwt;
        int P_n = hn ? (wt_n << 4) : 0;
        int m_n = hn ? min(16, E - P_n) : 1;

        // ---- issue next-tile csr FIRST ----
        int e_n = csr[hn ? (P_n + min(l15, m_n - 1)) : 0];

        // ---- issue current-tile f gather (bf16, 64 loads) ----
        float xs[16], xv0[16], xv1[16], xv2[16];
        #pragma unroll
        for (int i = 0; i < 16; ++i) {
            int si = rdlane(src, i);
            const unsigned short* fb = f + (size_t)si * NODE_F;
            xs[i]  = bf2f(fb[lane]);
            xv0[i] = bf2f(fb[64 + u]);
            xv1[i] = bf2f(fb[96 + u]);
            xv2[i] = bf2f(fb[128 + u]);
        }

        // ---- h compute (registers only; covers csr latency) ----
        float es[8] = {es0.x, es0.y, es0.z, es0.w, es1.x, es1.y, es1.z, es1.w};
        union { unsigned q[4]; bf16x8 v; } A0, A1;
        #pragma unroll
        for (int jp = 0; jp < 4; ++jp) {
            int k0 = lh * 8 + 2 * jp;
            float aL0 = 0.f, aL1 = 0.f, aH0 = 0.f, aH1 = 0.f;
            #pragma unroll
            for (int r = 0; r < 8; ++r) {
                float2 wl = *(const float2*)&s_fcW1[r * 64 + k0];
                float2 wh = *(const float2*)&s_fcW1[r * 64 + 32 + k0];
                aL0 = fmaf(es[r], wl.x, aL0);
                aL1 = fmaf(es[r], wl.y, aL1);
                aH0 = fmaf(es[r], wh.x, aH0);
                aH1 = fmaf(es[r], wh.y, aH1);
            }
            aL0 *= INV_SQRT8; aL1 *= INV_SQRT8; aH0 *= INV_SQRT8; aH1 *= INV_SQRT8;
            aL0 = aL0 / (1.f + __expf(-aL0));
            aL1 = aL1 / (1.f + __expf(-aL1));
            aH0 = aH0 / (1.f + __expf(-aH0));
            aH1 = aH1 / (1.f + __expf(-aH1));
            A0.q[jp] = bf16pack(aL0, aL1);
            A1.q[jp] = bf16pack(aH0, aH1);
        }

        // ---- issue next-tile metadata ----
        int src_n = edge_src[e_n];
        int dst_n = edge_dst[e_n];
        float4 ea_n = *(const float4*)(edge_attr + (size_t)e_n * 4);
        float4 es0_n, es1_n;
        {
            const float4* espn = (const float4*)(edge_scalars + (size_t)e_n * RADF);
            es0_n = espn[0]; es1_n = espn[1];
        }

        // ---- MFMA: w = h @ fcW2 / sqrt(64) ----
        #pragma unroll
        for (int cb = 0; cb < 12; ++cb) {
            bf16x8 b0 = *(const bf16x8*)&s_w2t[ lh      * 1536 + (cb * 16 + l15) * 8];
            bf16x8 b1 = *(const bf16x8*)&s_w2t[(4 + lh) * 1536 + (cb * 16 + l15) * 8];
            f32x4 acc = {0.f, 0.f, 0.f, 0.f};
            acc = __builtin_amdgcn_mfma_f32_16x16x32_bf16(A0.v, b0, acc, 0, 0, 0);
            acc = __builtin_amdgcn_mfma_f32_16x16x32_bf16(A1.v, b1, acc, 0, 0, 0);
            #pragma unroll
            for (int r = 0; r < 4; ++r)
                sw[(lh * 4 + r) * SWS + cb * 16 + l15] = f2bfu(acc[r] * INV_SQRT64);
        }

        // ---- TP + dst-segmented reduction (plain store if segment contained) ----
        float accA = 0.f, accB0 = 0.f, accB1 = 0.f, accB2 = 0.f;
        float accX0 = 0.f, accX1 = 0.f, accX2 = 0.f;
        int curd = rdlane(dst, 0);
        #pragma unroll
        for (int i = 0; i < 16; ++i) {
            if (i < m) {
                int di = rdlane(dst, i);
                if (di != curd) {
                    bool at = (curd == firstd) && (off_first < P);
                    FLUSH_AGG(curd, at);
                    accA = accB0 = accB1 = accB2 = 0.f;
                    accX0 = accX1 = accX2 = 0.f;
                    curd = di;
                }
                float4 eav = sea[i];     // wave-uniform LDS broadcast
                float W0 = bf2f(sw[i * SWS + lane]);
                float W1 = bf2f(sw[i * SWS + 64 + lane]);
                float W2 = bf2f(sw[i * SWS + 128 + lane]);
                accA = fmaf(W0 * xs[i], eav.x, accA);
                float bx = W1 * xs[i];
                accB0 = fmaf(bx, eav.y, accB0);
                accB1 = fmaf(bx, eav.z, accB1);
                accB2 = fmaf(bx, eav.w, accB2);
                if (lane < 32) {
                    float cc = W2 * eav.x;
                    accX0 = fmaf(cc, xv0[i], accX0);
                    accX1 = fmaf(cc, xv1[i], accX1);
                    accX2 = fmaf(cc, xv2[i], accX2);
                } else {
                    float dv = xv0[i] * eav.y + xv1[i] * eav.z + xv2[i] * eav.w;
                    accX0 = fmaf(W2 * INV_SQRT3, dv, accX0);
                }
            }
        }
        {
            bool at_fin = ((curd == firstd) && (off_first < P)) || (off_last > P + m);
            FLUSH_AGG(curd, at_fin);
        }

        if (!hn) break;
        wt = wt_n; P = P_n; m = m_n;
        src = src_n; dst = dst_n; ea = ea_n; es0 = es0_n; es1 = es1_n;
    }
}

// ---------------- kernel: output combine via MFMA, wave per 16 nodes ----------------
__global__ __launch_bounds__(256) void k_out(
    const float* __restrict__ node_input,
    const float* __restrict__ node_attr,
    const float* __restrict__ agg,
    const float* __restrict__ W_sc_s,
    const float* __restrict__ W_sc_v,
    const float* __restrict__ W2_s,
    const float* __restrict__ W2_v,
    const float* __restrict__ W3,
    float* __restrict__ out, int N)
{
    __shared__ unsigned short s_w2s[12 * 64 * 8];   // 12288 B
    __shared__ unsigned short s_wss[ 8 * 64 * 8];   //  8192 B
    __shared__ unsigned short s_w2v[12 * 32 * 8];   //  6144 B
    __shared__ unsigned short s_wsv[ 4 * 32 * 8];   //  2048 B
    __shared__ unsigned short s_w3 [12 * 16 * 8];   //  3072 B  -> 31744 B total

    const float pre = INV_SQRT10 * INV_SQRT96;
    int tid = threadIdx.x;

    for (int task = tid; task < 12 * 64; task += 256) {         // W2_s
        int col = task & 63, koct = task >> 6;
        const float* wp = W2_s + (size_t)(koct * 8) * MUL0 + col;
        unsigned pk0 = bf16pack(wp[0 * MUL0] * pre, wp[1 * MUL0] * pre);
        unsigned pk1 = bf16pack(wp[2 * MUL0] * pre, wp[3 * MUL0] * pre);
        unsigned pk2 = bf16pack(wp[4 * MUL0] * pre, wp[5 * MUL0] * pre);
        unsigned pk3 = bf16pack(wp[6 * MUL0] * pre, wp[7 * MUL0] * pre);
        *(uint4*)&s_w2s[task * 8] = make_uint4(pk0, pk1, pk2, pk3);
    }
    for (int task = tid; task < 8 * 64; task += 256) {          // W_sc_s
        int col = task & 63, koct = task >> 6;
        const float* wp = W_sc_s + (size_t)(koct * 8) * MUL0 + col;
        unsigned pk0 = bf16pack(wp[0 * MUL0] * INV_SQRT64, wp[1 * MUL0] * INV_SQRT64);
        unsigned pk1 = bf16pack(wp[2 * MUL0] * INV_SQRT64, wp[3 * MUL0] * INV_SQRT64);
        unsigned pk2 = bf16pack(wp[4 * MUL0] * INV_SQRT64, wp[5 * MUL0] * INV_SQRT64);
        unsigned pk3 = bf16pack(wp[6 * MUL0] * INV_SQRT64, wp[7 * MUL0] * INV_SQRT64);
        *(uint4*)&s_wss[task * 8] = make_uint4(pk0, pk1, pk2, pk3);
    }
    for (int task = tid; task < 12 * 32; task += 256) {         // W2_v
        int col = task & 31, koct = task >> 5;
        const float* wp = W2_v + (size_t)(koct * 8) * MUL1 + col;
        unsigned pk0 = bf16pack(wp[0 * MUL1] * pre, wp[1 * MUL1] * pre);
        unsigned pk1 = bf16pack(wp[2 * MUL1] * pre, wp[3 * MUL1] * pre);
        unsigned pk2 = bf16pack(wp[4 * MUL1] * pre, wp[5 * MUL1] * pre);
        unsigned pk3 = bf16pack(wp[6 * MUL1] * pre, wp[7 * MUL1] * pre);
        *(uint4*)&s_w2v[task * 8] = make_uint4(pk0, pk1, pk2, pk3);
    }
    for (int task = tid; task < 4 * 32; task += 256) {          // W_sc_v
        int col = task & 31, koct = task >> 5;
        const float* wp = W_sc_v + (size_t)(koct * 8) * MUL1 + col;
        unsigned pk0 = bf16pack(wp[0 * MUL1] * INV_SQRT32, wp[1 * MUL1] * INV_SQRT32);
        unsigned pk1 = bf16pack(wp[2 * MUL1] * INV_SQRT32, wp[3 * MUL1] * INV_SQRT32);
        unsigned pk2 = bf16pack(wp[4 * MUL1] * INV_SQRT32, wp[5 * MUL1] * INV_SQRT32);
        unsigned pk3 = bf16pack(wp[6 * MUL1] * INV_SQRT32, wp[7 * MUL1] * INV_SQRT32);
        *(uint4*)&s_wsv[task * 8] = make_uint4(pk0, pk1, pk2, pk3);
    }
    for (int task = tid; task < 12 * 16; task += 256) {         // W3 block
        int col = task & 15, koct = task >> 4;
        const float sc3 = 0.1f * pre;
        unsigned pk0 = 0, pk1 = 0, pk2 = 0, pk3 = 0;
        if (col == 0) {
            const float* wp = W3 + koct * 8;
            pk0 = bf16pack(wp[0] * sc3, wp[1] * sc3);
            pk1 = bf16pack(wp[2] * sc3, wp[3] * sc3);
            pk2 = bf16pack(wp[4] * sc3, wp[5] * sc3);
            pk3 = bf16pack(wp[6] * sc3, wp[7] * sc3);
        }
        *(uint4*)&s_w3[task * 8] = make_uint4(pk0, pk1, pk2, pk3);
    }
    __syncthreads();

    int lane = tid & 63;
    int wv = tid >> 6;
    int l15 = lane & 15, lh = lane >> 4;
    int ntiles = (N + 15) >> 4;

    for (int tile = blockIdx.x * 4 + wv; tile < ntiles; tile += gridDim.x * 4) {
        int n0 = tile << 4;
        int m = min(16, N - n0);
        int nrow = n0 + min(l15, m - 1);
        const float* agn = agg + (size_t)nrow * AGG_F;
        const float* inn = node_input + (size_t)nrow * NODE_F;

        bf16x8 aggA[3], inS[2];
        #pragma unroll
        for (int kk = 0; kk < 3; ++kk) {
            const float* p0 = agn + kk * 32 + lh * 8;
            aggA[kk] = cvt8(*(const float4*)p0, *(const float4*)(p0 + 4));
        }
        #pragma unroll
        for (int kk = 0; kk < 2; ++kk) {
            const float* p0 = inn + kk * 32 + lh * 8;
            inS[kk] = cvt8(*(const float4*)p0, *(const float4*)(p0 + 4));
        }

        f32x4 convS[4], scS[4], angD = {0.f, 0.f, 0.f, 0.f};
        #pragma unroll
        for (int cb = 0; cb < 4; ++cb) {
            f32x4 a = {0.f, 0.f, 0.f, 0.f};
            #pragma unroll
            for (int kk = 0; kk < 3; ++kk) {
                bf16x8 b = *(const bf16x8*)&s_w2s[(((kk * 4 + lh) * 64) + cb * 16 + l15) * 8];
                a = __builtin_amdgcn_mfma_f32_16x16x32_bf16(aggA[kk], b, a, 0, 0, 0);
            }
            convS[cb] = a;
            f32x4 s = {0.f, 0.f, 0.f, 0.f};
            #pragma unroll
            for (int kk = 0; kk < 2; ++kk) {
                bf16x8 b = *(const bf16x8*)&s_wss[(((kk * 4 + lh) * 64) + cb * 16 + l15) * 8];
                s = __builtin_amdgcn_mfma_f32_16x16x32_bf16(inS[kk], b, s, 0, 0, 0);
            }
            scS[cb] = s;
        }
        #pragma unroll
        for (int kk = 0; kk < 3; ++kk) {
            bf16x8 b = *(const bf16x8*)&s_w3[(((kk * 4 + lh) * 16) + l15) * 8];
            angD = __builtin_amdgcn_mfma_f32_16x16x32_bf16(aggA[kk], b, angD, 0, 0, 0);
        }

        float attr[4], cs[4], sn[4];
        #pragma unroll
        for (int r = 0; r < 4; ++r) {
            attr[r] = node_attr[n0 + min(lh * 4 + r, m - 1)];
            float ang = __shfl(angD[r], lane & 48) * attr[r];
            cs[r] = cosf(ang);
            sn[r] = sinf(ang);
        }

        #pragma unroll
        for (int cb = 0; cb < 4; ++cb)
            #pragma unroll
            for (int r = 0; r < 4; ++r) {
                int node = lh * 4 + r;
                if (node < m)
                    out[(size_t)(n0 + node) * NODE_F + cb * 16 + l15] =
                        attr[r] * (cs[r] * scS[cb][r] + sn[r] * convS[cb][r]);
            }

        #pragma unroll
        for (int d = 0; d < 3; ++d) {
            bf16x8 aggV[3], inV;
            #pragma unroll
            for (int kk = 0; kk < 3; ++kk) {
                const float* p0 = agn + 96 + d * 96 + kk * 32 + lh * 8;
                aggV[kk] = cvt8(*(const float4*)p0, *(const float4*)(p0 + 4));
            }
            {
                float t[8];
                #pragma unroll
                for (int j = 0; j < 8; ++j)
                    t[j] = inn[64 + (lh * 8 + j) * 3 + d];
                inV = cvt8(make_float4(t[0], t[1], t[2], t[3]),
                           make_float4(t[4], t[5], t[6], t[7]));
            }
            #pragma unroll
            for (int cb = 0; cb < 2; ++cb) {
                f32x4 a = {0.f, 0.f, 0.f, 0.f};
                #pragma unroll
                for (int kk = 0; kk < 3; ++kk) {
                    bf16x8 b = *(const bf16x8*)&s_w2v[(((kk * 4 + lh) * 32) + cb * 16 + l15) * 8];
                    a = __builtin_amdgcn_mfma_f32_16x16x32_bf16(aggV[kk], b, a, 0, 0, 0);
                }
                f32x4 s = {0.f, 0.f, 0.f, 0.f};
                {
                    bf16x8 b = *(const bf16x8*)&s_wsv[((lh * 32) + cb * 16 + l15) * 8];
                    s = __builtin_amdgcn_mfma_f32_16x16x32_bf16(inV, b, s, 0, 0, 0);
                }
                #pragma unroll
                for (int r = 0; r < 4; ++r) {
                    int node = lh * 4 + r;
                    if (node < m)
                        out[(size_t)(n0 + node) * NODE_F + 64 + (cb * 16 + l15) * 3 + d] =
                            attr[r] * (cs[r] * s[r] + sn[r] * a[r]);
                }
            }
        }
    }
}

extern "C" void kernel_launch(void* const* d_in, const int* in_sizes, int n_in,
                              void* d_out, int out_size, void* d_ws, size_t ws_size,
                              hipStream_t stream)
{
    const float* node_input   = (const float*)d_in[0];
    const float* node_attr    = (const float*)d_in[1];
    const float* edge_attr    = (const float*)d_in[2];
    const float* edge_scalars = (const float*)d_in[3];
    const float* W_sc_s       = (const float*)d_in[4];
    const float* W_sc_v       = (const float*)d_in[5];
    const float* W1_s         = (const float*)d_in[6];
    const float* W1_v         = (const float*)d_in[7];
    const float* W2_s         = (const float*)d_in[8];
    const float* W2_v         = (const float*)d_in[9];
    const float* W3           = (const float*)d_in[10];
    const float* fcW1         = (const float*)d_in[11];
    const float* fcW2         = (const float*)d_in[12];
    const int*   edge_src     = (const int*)d_in[13];
    const int*   edge_dst     = (const int*)d_in[14];
    float* out = (float*)d_out;

    const int N = in_sizes[1];
    const int E = in_sizes[13];
    const int Np = (N + 3) & ~3;          // pad for int4 scan

    // ---- workspace layout ----
    char* p = (char*)d_ws;
    float* agg = (float*)p;            p += (size_t)N * AGG_F * sizeof(float);
    unsigned short* fbf = (unsigned short*)p;  p += (size_t)N * NODE_F * sizeof(unsigned short);
    int*   deg = (int*)p;              p += (size_t)Np * sizeof(int);
    int*   cur = (int*)p;              p += (size_t)Np * sizeof(int);
    int*   off = (int*)p;              p += (size_t)(Np + 4) * sizeof(int);
    int*   csr = (int*)p;              p += (size_t)E * sizeof(int);
    int*   bsum = (int*)p;             p += 64 * sizeof(int);

    hipMemsetAsync(deg, 0, (size_t)Np * sizeof(int), stream);
    hipMemsetAsync(agg, 0, (size_t)N * AGG_F * sizeof(float), stream);

    int eb = (E + 255) / 256;
    k_count<<<eb, 256, 0, stream>>>(edge_dst, deg, E);

    int ng4 = (N + 3) >> 2;
    int nb = (ng4 + 1023) / 1024;
    k_scan_a<<<nb, 1024, 0, stream>>>(deg, off, bsum, N);
    k_scan_b<<<nb, 1024, 0, stream>>>(off, cur, bsum, N, nb);
    k_scatter<<<eb, 256, 0, stream>>>(edge_dst, cur, csr, E);

    int ntiles = (N + 15) / 16;
    int gridL = (ntiles + 3) / 4;
    k_node_lin<<<gridL, 256, 0, stream>>>(node_input, node_attr, W1_s, W1_v, fbf, N);

    int nwt = (E + 15) / 16;
    int gridF = (nwt + 7) / 8;
    if (gridF > 1024) gridF = 1024;
    k_edge_fused<<<gridF, 512, 0, stream>>>(fbf, edge_scalars, edge_attr, fcW1, fcW2,
                                            edge_src, edge_dst, csr, off, agg, E);

    int gridO = (ntiles + 3) / 4;
    if (gridO > 640) gridO = 640;
    k_out<<<gridO, 256, 0, stream>>>(node_input, node_attr, agg,
                                     W_sc_s, W_sc_v, W2_s, W2_v, W3, out, N);
}

// Round 16
// 210.335 us; speedup vs baseline: 1.1966x; 1.0477x over previous
//
#include <hip/hip_runtime.h>
#include <math.h>

#define MUL0 64
#define MUL1 32
#define RADF 8
#define HIDF 64
#define WNUM 192
#define NODE_F 160   // 64 + 96
#define AGG_F  384   // A(64) | D(32) | mv_d0(96) | mv_d1(96) | mv_d2(96)
#define SWS 200      // s_w row stride (shorts)

#define INV_SQRT64 0.125f
#define INV_SQRT32 0.17677669529663687f
#define INV_SQRT8  0.35355339059327373f
#define INV_SQRT96 0.10206207261596575f
#define INV_SQRT10 0.31622776601683794f
#define INV_SQRT3  0.5773502691896258f

typedef __attribute__((ext_vector_type(8))) short bf16x8;
typedef __attribute__((ext_vector_type(4))) float f32x4;

__device__ __forceinline__ float bf2f(unsigned short u) {
    return __uint_as_float((unsigned)u << 16);
}
__device__ __forceinline__ unsigned short f2bfu(float x) {
    unsigned ua = __float_as_uint(x);
    return (unsigned short)((ua + 0x7FFF + ((ua >> 16) & 1)) >> 16);
}
__device__ __forceinline__ unsigned bf16pack(float a, float b) {
    unsigned ua = __float_as_uint(a);
    unsigned ub = __float_as_uint(b);
    ua = (ua + 0x7FFF + ((ua >> 16) & 1)) >> 16;
    ub = (ub + 0x7FFF + ((ub >> 16) & 1)) >> 16;
    return ua | (ub << 16);
}
__device__ __forceinline__ int rdlane(int v, int i) {
    return __builtin_amdgcn_readlane(v, i);
}
__device__ __forceinline__ bf16x8 cvt8(float4 a, float4 b) {
    union { unsigned q[4]; bf16x8 v; } r;
    r.q[0] = bf16pack(a.x, a.y);
    r.q[1] = bf16pack(a.z, a.w);
    r.q[2] = bf16pack(b.x, b.y);
    r.q[3] = bf16pack(b.z, b.w);
    return r.v;
}
// load 8 f32 from agg row + add bf16 ovf partials from tiles tA..tB, then pack bf16x8
__device__ __forceinline__ bf16x8 load8ovf(const float* agn,
                                           const unsigned short* ovf16,
                                           int tA, int tB, int base)
{
    float4 a = *(const float4*)(agn + base);
    float4 b = *(const float4*)(agn + base + 4);
    float v[8] = {a.x, a.y, a.z, a.w, b.x, b.y, b.z, b.w};
    for (int t = tA; t <= tB; ++t) {
        const unsigned short* ov = ovf16 + (size_t)t * AGG_F + base;
        #pragma unroll
        for (int j = 0; j < 8; ++j)
            v[j] += bf2f(ov[j]);
    }
    return cvt8(make_float4(v[0], v[1], v[2], v[3]),
                make_float4(v[4], v[5], v[6], v[7]));
}

// ---------------- kernel: f = _lin(...) via MFMA, wave per 16 nodes, bf16 output ----------------
// f layout (bf16): [n][0:64]=s ; [n][64 + d*32 + u] = v[u][d]
__global__ __launch_bounds__(256) void k_node_lin(
    const float* __restrict__ node_input,
    const float* __restrict__ node_attr,
    const float* __restrict__ W1_s,
    const float* __restrict__ W1_v,
    unsigned short* __restrict__ f, int N)
{
    __shared__ unsigned short s_w1s[8 * 64 * 8];   // 8 KB
    __shared__ unsigned short s_w1v[4 * 32 * 8];   // 2 KB
    int tid = threadIdx.x;

    for (int task = tid; task < 8 * 64; task += 256) {
        int col = task & 63, koct = task >> 6;
        const float* wp = W1_s + (size_t)(koct * 8) * MUL0 + col;
        unsigned pk0 = bf16pack(wp[0 * MUL0] * INV_SQRT64, wp[1 * MUL0] * INV_SQRT64);
        unsigned pk1 = bf16pack(wp[2 * MUL0] * INV_SQRT64, wp[3 * MUL0] * INV_SQRT64);
        unsigned pk2 = bf16pack(wp[4 * MUL0] * INV_SQRT64, wp[5 * MUL0] * INV_SQRT64);
        unsigned pk3 = bf16pack(wp[6 * MUL0] * INV_SQRT64, wp[7 * MUL0] * INV_SQRT64);
        *(uint4*)&s_w1s[task * 8] = make_uint4(pk0, pk1, pk2, pk3);
    }
    for (int task = tid; task < 4 * 32; task += 256) {
        int col = task & 31, koct = task >> 5;
        const float* wp = W1_v + (size_t)(koct * 8) * MUL1 + col;
        unsigned pk0 = bf16pack(wp[0 * MUL1] * INV_SQRT32, wp[1 * MUL1] * INV_SQRT32);
        unsigned pk1 = bf16pack(wp[2 * MUL1] * INV_SQRT32, wp[3 * MUL1] * INV_SQRT32);
        unsigned pk2 = bf16pack(wp[4 * MUL1] * INV_SQRT32, wp[5 * MUL1] * INV_SQRT32);
        unsigned pk3 = bf16pack(wp[6 * MUL1] * INV_SQRT32, wp[7 * MUL1] * INV_SQRT32);
        *(uint4*)&s_w1v[task * 8] = make_uint4(pk0, pk1, pk2, pk3);
    }
    __syncthreads();

    int lane = tid & 63;
    int wv = tid >> 6;
    int l15 = lane & 15, lh = lane >> 4;
    int ntiles = (N + 15) >> 4;

    for (int tile = blockIdx.x * 4 + wv; tile < ntiles; tile += gridDim.x * 4) {
        int n0 = tile << 4;
        int m = min(16, N - n0);
        int nrow = n0 + min(l15, m - 1);
        const float* inn = node_input + (size_t)nrow * NODE_F;

        float attr[4];
        #pragma unroll
        for (int r = 0; r < 4; ++r)
            attr[r] = node_attr[n0 + min(lh * 4 + r, m - 1)];

        bf16x8 inS[2];
        #pragma unroll
        for (int kk = 0; kk < 2; ++kk) {
            const float* p0 = inn + kk * 32 + lh * 8;
            inS[kk] = cvt8(*(const float4*)p0, *(const float4*)(p0 + 4));
        }
        #pragma unroll
        for (int cb = 0; cb < 4; ++cb) {
            f32x4 a = {0.f, 0.f, 0.f, 0.f};
            #pragma unroll
            for (int kk = 0; kk < 2; ++kk) {
                bf16x8 b = *(const bf16x8*)&s_w1s[(((kk * 4 + lh) * 64) + cb * 16 + l15) * 8];
                a = __builtin_amdgcn_mfma_f32_16x16x32_bf16(inS[kk], b, a, 0, 0, 0);
            }
            #pragma unroll
            for (int r = 0; r < 4; ++r) {
                int node = lh * 4 + r;
                if (node < m)
                    f[(size_t)(n0 + node) * NODE_F + cb * 16 + l15] = f2bfu(a[r] * attr[r]);
            }
        }

        #pragma unroll
        for (int d = 0; d < 3; ++d) {
            float t[8];
            #pragma unroll
            for (int j = 0; j < 8; ++j)
                t[j] = inn[64 + (lh * 8 + j) * 3 + d];
            bf16x8 inV = cvt8(make_float4(t[0], t[1], t[2], t[3]),
                              make_float4(t[4], t[5], t[6], t[7]));
            #pragma unroll
            for (int cb = 0; cb < 2; ++cb) {
                bf16x8 b = *(const bf16x8*)&s_w1v[((lh * 32) + cb * 16 + l15) * 8];
                f32x4 a = {0.f, 0.f, 0.f, 0.f};
                a = __builtin_amdgcn_mfma_f32_16x16x32_bf16(inV, b, a, 0, 0, 0);
                #pragma unroll
                for (int r = 0; r < 4; ++r) {
                    int node = lh * 4 + r;
                    if (node < m)
                        f[(size_t)(n0 + node) * NODE_F + 64 + d * 32 + cb * 16 + l15] =
                            f2bfu(a[r] * attr[r]);
                }
            }
        }
    }
}

// ---------------- CSR build ----------------
__global__ void k_count(const int* __restrict__ edge_dst, int* deg, int E)
{
    int e = blockIdx.x * blockDim.x + threadIdx.x;
    if (e < E) atomicAdd(&deg[edge_dst[e]], 1);
}

// multi-block scan: A = per-block local scan + block sums
__global__ __launch_bounds__(1024) void k_scan_a(const int* __restrict__ deg,
                                                 int* __restrict__ off,
                                                 int* __restrict__ bsum, int N)
{
    __shared__ int swsum[16];
    __shared__ int swoff[16];
    __shared__ int stot;
    int lane = threadIdx.x & 63, wid = threadIdx.x >> 6;
    int ng4 = (N + 3) >> 2;
    int g = blockIdx.x * 1024 + threadIdx.x;
    int4 v = make_int4(0, 0, 0, 0);
    if (g < ng4) v = ((const int4*)deg)[g];
    int s = v.x + v.y + v.z + v.w;
    int val = s;
    #pragma unroll
    for (int sh = 1; sh < 64; sh <<= 1) {
        int t = __shfl_up(val, sh);
        if (lane >= sh) val += t;
    }
    if (lane == 63) swsum[wid] = val;
    __syncthreads();
    if (threadIdx.x < 16) {
        int x = swsum[threadIdx.x];
        int xv = x;
        #pragma unroll
        for (int sh = 1; sh < 16; sh <<= 1) {
            int t = __shfl_up(xv, sh);
            if ((int)threadIdx.x >= sh) xv += t;
        }
        swoff[threadIdx.x] = xv - x;
        if (threadIdx.x == 15) stot = xv;
    }
    __syncthreads();
    if (g < ng4) {
        int b0 = swoff[wid] + (val - s);
        int4 o;
        o.x = b0; o.y = b0 + v.x; o.z = o.y + v.y; o.w = o.z + v.z;
        ((int4*)off)[g] = o;
    }
    if (threadIdx.x == 0) bsum[blockIdx.x] = stot;
}

// B: add block bases, write cur, zero agg rows of deg-0 nodes
__global__ __launch_bounds__(1024) void k_scan_b(int* __restrict__ off,
                                                 int* __restrict__ cur,
                                                 const int* __restrict__ bsum,
                                                 float* __restrict__ agg,
                                                 const int* __restrict__ deg,
                                                 int N, int nb)
{
    __shared__ int sbase;
    if (threadIdx.x == 0) {
        int s = 0;
        for (int j = 0; j < (int)blockIdx.x; ++j) s += bsum[j];
        sbase = s;
    }
    __syncthreads();
    int base = sbase;
    int ng4 = (N + 3) >> 2;
    int g = blockIdx.x * 1024 + threadIdx.x;
    if (g < ng4) {
        int4 o = ((int4*)off)[g];
        o.x += base; o.y += base; o.z += base; o.w += base;
        ((int4*)off)[g] = o;
        ((int4*)cur)[g] = o;
        int4 d = ((const int4*)deg)[g];
        int n0 = g * 4;
        #pragma unroll
        for (int q = 0; q < 4; ++q) {
            int dq = (q == 0) ? d.x : (q == 1) ? d.y : (q == 2) ? d.z : d.w;
            int nq = n0 + q;
            if (dq == 0 && nq < N) {
                float4* row = (float4*)(agg + (size_t)nq * AGG_F);
                float4 z = make_float4(0.f, 0.f, 0.f, 0.f);
                for (int j = 0; j < AGG_F / 4; ++j) row[j] = z;
            }
        }
    }
}

__global__ void k_scatter(const int* __restrict__ edge_dst,
                          int* cur, int* __restrict__ csr, int E)
{
    int e = blockIdx.x * blockDim.x + threadIdx.x;
    if (e < E) {
        int d = edge_dst[e];
        int pos = atomicAdd(&cur[d], 1);
        csr[pos] = e;
    }
}

// ---------------- fused edge kernel: 16-edge tiles, ovf-buffer flush (no atomics) ----------------
// Flush rule: if the segment being flushed is this tile's FIRST segment and it started
// in an earlier tile -> write bf16 partial to ovf[wt]; else plain f32 store to agg
// (the tile containing a segment's start owns agg[n]; k_out adds ovf of later tiles).
#define FLUSH_AGG(node, OVF)                                         \
    do {                                                             \
        if (OVF) {                                                   \
            unsigned short* ov = ovf16 + (size_t)wt * AGG_F;         \
            ov[lane] = f2bfu(accA);                                  \
            ov[96  + lane] = f2bfu(accB0);                           \
            ov[192 + lane] = f2bfu(accB1);                           \
            ov[288 + lane] = f2bfu(accB2);                           \
            if (lane < 32) {                                         \
                ov[160 + u] = f2bfu(accX0);                          \
                ov[256 + u] = f2bfu(accX1);                          \
                ov[352 + u] = f2bfu(accX2);                          \
            } else {                                                 \
                ov[64 + u] = f2bfu(accX0);                           \
            }                                                        \
        } else {                                                     \
            float* an = agg + (size_t)(node) * AGG_F;                \
            an[lane] = accA;                                         \
            an[96  + lane] = accB0;                                  \
            an[192 + lane] = accB1;                                  \
            an[288 + lane] = accB2;                                  \
            if (lane < 32) {                                         \
                an[160 + u] = accX0;                                 \
                an[256 + u] = accX1;                                 \
                an[352 + u] = accX2;                                 \
            } else {                                                 \
                an[64 + u] = accX0;                                  \
            }                                                        \
        }                                                            \
    } while (0)

__global__ __launch_bounds__(512, 2) void k_edge_fused(
    const unsigned short* __restrict__ f,
    const float* __restrict__ edge_scalars,
    const float* __restrict__ edge_attr,
    const float* __restrict__ fcW1,
    const float* __restrict__ fcW2,
    const int* __restrict__ edge_src,
    const int* __restrict__ edge_dst,
    const int* __restrict__ csr,
    const int* __restrict__ off,
    float* __restrict__ agg,
    unsigned short* __restrict__ ovf16, int E)
{
    __shared__ unsigned short s_w2t[8 * 192 * 8];   // 24576 B
    __shared__ unsigned short s_w[8][16 * SWS];     // 51200 B
    __shared__ float s_fcW1[512];                   //  2048 B
    __shared__ float4 s_ea8[8][16];                 //  2048 B  -> 79872 B total

    int tid  = threadIdx.x;
    int lane = tid & 63;
    int wv   = tid >> 6;                 // 0..7
    int l15  = lane & 15, lh = lane >> 4;
    int u    = lane & 31;

    for (int task = tid; task < 1536; task += 512) {
        int col = task % 192, oct = task / 192;
        const float* wp = fcW2 + (size_t)(oct * 8) * WNUM + col;
        unsigned pk0 = bf16pack(wp[0 * WNUM], wp[1 * WNUM]);
        unsigned pk1 = bf16pack(wp[2 * WNUM], wp[3 * WNUM]);
        unsigned pk2 = bf16pack(wp[4 * WNUM], wp[5 * WNUM]);
        unsigned pk3 = bf16pack(wp[6 * WNUM], wp[7 * WNUM]);
        *(uint4*)&s_w2t[oct * 1536 + col * 8] = make_uint4(pk0, pk1, pk2, pk3);
    }
    for (int i = tid; i < 512; i += 512)
        s_fcW1[i] = fcW1[i];
    __syncthreads();      // the only block barrier

    unsigned short* sw = s_w[wv];
    float4* sea = s_ea8[wv];
    int nwt = (E + 15) >> 4;
    int stride8 = gridDim.x * 8;

    int wt = blockIdx.x * 8 + wv;
    if (wt >= nwt) return;

    // ---- prologue: metadata chain for first tile ----
    int P = wt << 4;
    int m = min(16, E - P);
    int e0 = csr[P + min(l15, m - 1)];
    int src = edge_src[e0];
    int dst = edge_dst[e0];
    float4 ea = *(const float4*)(edge_attr + (size_t)e0 * 4);
    float4 es0, es1;
    {
        const float4* esp = (const float4*)(edge_scalars + (size_t)e0 * RADF);
        es0 = esp[0]; es1 = esp[1];
    }

    while (true) {
        // ---- per-wave ea table ----
        if (lh == 0) sea[l15] = ea;

        // ---- first-segment boundary info ----
        int firstd = rdlane(dst, 0);
        int off_first = off[firstd];

        int wt_n = wt + stride8;
        bool hn = wt_n < nwt;
        int P_n = hn ? (wt_n << 4) : 0;
        int m_n = hn ? min(16, E - P_n) : 1;

        // ---- issue next-tile csr FIRST ----
        int e_n = csr[hn ? (P_n + min(l15, m_n - 1)) : 0];

        // ---- issue current-tile f gather (bf16, 64 loads) ----
        float xs[16], xv0[16], xv1[16], xv2[16];
        #pragma unroll
        for (int i = 0; i < 16; ++i) {
            int si = rdlane(src, i);
            const unsigned short* fb = f + (size_t)si * NODE_F;
            xs[i]  = bf2f(fb[lane]);
            xv0[i] = bf2f(fb[64 + u]);
            xv1[i] = bf2f(fb[96 + u]);
            xv2[i] = bf2f(fb[128 + u]);
        }

        // ---- h compute (registers only) ----
        float es[8] = {es0.x, es0.y, es0.z, es0.w, es1.x, es1.y, es1.z, es1.w};
        union { unsigned q[4]; bf16x8 v; } A0, A1;
        #pragma unroll
        for (int jp = 0; jp < 4; ++jp) {
            int k0 = lh * 8 + 2 * jp;
            float aL0 = 0.f, aL1 = 0.f, aH0 = 0.f, aH1 = 0.f;
            #pragma unroll
            for (int r = 0; r < 8; ++r) {
                float2 wl = *(const float2*)&s_fcW1[r * 64 + k0];
                float2 wh = *(const float2*)&s_fcW1[r * 64 + 32 + k0];
                aL0 = fmaf(es[r], wl.x, aL0);
                aL1 = fmaf(es[r], wl.y, aL1);
                aH0 = fmaf(es[r], wh.x, aH0);
                aH1 = fmaf(es[r], wh.y, aH1);
            }
            aL0 *= INV_SQRT8; aL1 *= INV_SQRT8; aH0 *= INV_SQRT8; aH1 *= INV_SQRT8;
            aL0 = aL0 / (1.f + __expf(-aL0));
            aL1 = aL1 / (1.f + __expf(-aL1));
            aH0 = aH0 / (1.f + __expf(-aH0));
            aH1 = aH1 / (1.f + __expf(-aH1));
            A0.q[jp] = bf16pack(aL0, aL1);
            A1.q[jp] = bf16pack(aH0, aH1);
        }

        // ---- issue next-tile metadata ----
        int src_n = edge_src[e_n];
        int dst_n = edge_dst[e_n];
        float4 ea_n = *(const float4*)(edge_attr + (size_t)e_n * 4);
        float4 es0_n, es1_n;
        {
            const float4* espn = (const float4*)(edge_scalars + (size_t)e_n * RADF);
            es0_n = espn[0]; es1_n = espn[1];
        }

        // ---- MFMA: w = h @ fcW2 / sqrt(64) ----
        #pragma unroll
        for (int cb = 0; cb < 12; ++cb) {
            bf16x8 b0 = *(const bf16x8*)&s_w2t[ lh      * 1536 + (cb * 16 + l15) * 8];
            bf16x8 b1 = *(const bf16x8*)&s_w2t[(4 + lh) * 1536 + (cb * 16 + l15) * 8];
            f32x4 acc = {0.f, 0.f, 0.f, 0.f};
            acc = __builtin_amdgcn_mfma_f32_16x16x32_bf16(A0.v, b0, acc, 0, 0, 0);
            acc = __builtin_amdgcn_mfma_f32_16x16x32_bf16(A1.v, b1, acc, 0, 0, 0);
            #pragma unroll
            for (int r = 0; r < 4; ++r)
                sw[(lh * 4 + r) * SWS + cb * 16 + l15] = f2bfu(acc[r] * INV_SQRT64);
        }

        // ---- TP + dst-segmented reduction (ovf partial or plain store) ----
        float accA = 0.f, accB0 = 0.f, accB1 = 0.f, accB2 = 0.f;
        float accX0 = 0.f, accX1 = 0.f, accX2 = 0.f;
        int curd = rdlane(dst, 0);
        #pragma unroll
        for (int i = 0; i < 16; ++i) {
            if (i < m) {
                int di = rdlane(dst, i);
                if (di != curd) {
                    bool ov = (curd == firstd) && (off_first < P);
                    FLUSH_AGG(curd, ov);
                    accA = accB0 = accB1 = accB2 = 0.f;
                    accX0 = accX1 = accX2 = 0.f;
                    curd = di;
                }
                float4 eav = sea[i];
                float W0 = bf2f(sw[i * SWS + lane]);
                float W1 = bf2f(sw[i * SWS + 64 + lane]);
                float W2 = bf2f(sw[i * SWS + 128 + lane]);
                accA = fmaf(W0 * xs[i], eav.x, accA);
                float bx = W1 * xs[i];
                accB0 = fmaf(bx, eav.y, accB0);
                accB1 = fmaf(bx, eav.z, accB1);
                accB2 = fmaf(bx, eav.w, accB2);
                if (lane < 32) {
                    float cc = W2 * eav.x;
                    accX0 = fmaf(cc, xv0[i], accX0);
                    accX1 = fmaf(cc, xv1[i], accX1);
                    accX2 = fmaf(cc, xv2[i], accX2);
                } else {
                    float dv = xv0[i] * eav.y + xv1[i] * eav.z + xv2[i] * eav.w;
                    accX0 = fmaf(W2 * INV_SQRT3, dv, accX0);
                }
            }
        }
        {
            bool ov_fin = (curd == firstd) && (off_first < P);
            FLUSH_AGG(curd, ov_fin);
        }

        if (!hn) break;
        wt = wt_n; P = P_n; m = m_n;
        src = src_n; dst = dst_n; ea = ea_n; es0 = es0_n; es1 = es1_n;
    }
}

// ---------------- kernel: output combine via MFMA, wave per 16 nodes (+ovf fixup) ----------------
__global__ __launch_bounds__(256) void k_out(
    const float* __restrict__ node_input,
    const float* __restrict__ node_attr,
    const float* __restrict__ agg,
    const unsigned short* __restrict__ ovf16,
    const int* __restrict__ off,
    const float* __restrict__ W_sc_s,
    const float* __restrict__ W_sc_v,
    const float* __restrict__ W2_s,
    const float* __restrict__ W2_v,
    const float* __restrict__ W3,
    float* __restrict__ out, int N)
{
    __shared__ unsigned short s_w2s[12 * 64 * 8];   // 12288 B
    __shared__ unsigned short s_wss[ 8 * 64 * 8];   //  8192 B
    __shared__ unsigned short s_w2v[12 * 32 * 8];   //  6144 B
    __shared__ unsigned short s_wsv[ 4 * 32 * 8];   //  2048 B
    __shared__ unsigned short s_w3 [12 * 16 * 8];   //  3072 B  -> 31744 B total

    const float pre = INV_SQRT10 * INV_SQRT96;
    int tid = threadIdx.x;

    for (int task = tid; task < 12 * 64; task += 256) {         // W2_s
        int col = task & 63, koct = task >> 6;
        const float* wp = W2_s + (size_t)(koct * 8) * MUL0 + col;
        unsigned pk0 = bf16pack(wp[0 * MUL0] * pre, wp[1 * MUL0] * pre);
        unsigned pk1 = bf16pack(wp[2 * MUL0] * pre, wp[3 * MUL0] * pre);
        unsigned pk2 = bf16pack(wp[4 * MUL0] * pre, wp[5 * MUL0] * pre);
        unsigned pk3 = bf16pack(wp[6 * MUL0] * pre, wp[7 * MUL0] * pre);
        *(uint4*)&s_w2s[task * 8] = make_uint4(pk0, pk1, pk2, pk3);
    }
    for (int task = tid; task < 8 * 64; task += 256) {          // W_sc_s
        int col = task & 63, koct = task >> 6;
        const float* wp = W_sc_s + (size_t)(koct * 8) * MUL0 + col;
        unsigned pk0 = bf16pack(wp[0 * MUL0] * INV_SQRT64, wp[1 * MUL0] * INV_SQRT64);
        unsigned pk1 = bf16pack(wp[2 * MUL0] * INV_SQRT64, wp[3 * MUL0] * INV_SQRT64);
        unsigned pk2 = bf16pack(wp[4 * MUL0] * INV_SQRT64, wp[5 * MUL0] * INV_SQRT64);
        unsigned pk3 = bf16pack(wp[6 * MUL0] * INV_SQRT64, wp[7 * MUL0] * INV_SQRT64);
        *(uint4*)&s_wss[task * 8] = make_uint4(pk0, pk1, pk2, pk3);
    }
    for (int task = tid; task < 12 * 32; task += 256) {         // W2_v
        int col = task & 31, koct = task >> 5;
        const float* wp = W2_v + (size_t)(koct * 8) * MUL1 + col;
        unsigned pk0 = bf16pack(wp[0 * MUL1] * pre, wp[1 * MUL1] * pre);
        unsigned pk1 = bf16pack(wp[2 * MUL1] * pre, wp[3 * MUL1] * pre);
        unsigned pk2 = bf16pack(wp[4 * MUL1] * pre, wp[5 * MUL1] * pre);
        unsigned pk3 = bf16pack(wp[6 * MUL1] * pre, wp[7 * MUL1] * pre);
        *(uint4*)&s_w2v[task * 8] = make_uint4(pk0, pk1, pk2, pk3);
    }
    for (int task = tid; task < 4 * 32; task += 256) {          // W_sc_v
        int col = task & 31, koct = task >> 5;
        const float* wp = W_sc_v + (size_t)(koct * 8) * MUL1 + col;
        unsigned pk0 = bf16pack(wp[0 * MUL1] * INV_SQRT32, wp[1 * MUL1] * INV_SQRT32);
        unsigned pk1 = bf16pack(wp[2 * MUL1] * INV_SQRT32, wp[3 * MUL1] * INV_SQRT32);
        unsigned pk2 = bf16pack(wp[4 * MUL1] * INV_SQRT32, wp[5 * MUL1] * INV_SQRT32);
        unsigned pk3 = bf16pack(wp[6 * MUL1] * INV_SQRT32, wp[7 * MUL1] * INV_SQRT32);
        *(uint4*)&s_wsv[task * 8] = make_uint4(pk0, pk1, pk2, pk3);
    }
    for (int task = tid; task < 12 * 16; task += 256) {         // W3 block
        int col = task & 15, koct = task >> 4;
        const float sc3 = 0.1f * pre;
        unsigned pk0 = 0, pk1 = 0, pk2 = 0, pk3 = 0;
        if (col == 0) {
            const float* wp = W3 + koct * 8;
            pk0 = bf16pack(wp[0] * sc3, wp[1] * sc3);
            pk1 = bf16pack(wp[2] * sc3, wp[3] * sc3);
            pk2 = bf16pack(wp[4] * sc3, wp[5] * sc3);
            pk3 = bf16pack(wp[6] * sc3, wp[7] * sc3);
        }
        *(uint4*)&s_w3[task * 8] = make_uint4(pk0, pk1, pk2, pk3);
    }
    __syncthreads();

    int lane = tid & 63;
    int wv = tid >> 6;
    int l15 = lane & 15, lh = lane >> 4;
    int ntiles = (N + 15) >> 4;

    for (int tile = blockIdx.x * 4 + wv; tile < ntiles; tile += gridDim.x * 4) {
        int n0 = tile << 4;
        int m = min(16, N - n0);
        int nrow = n0 + min(l15, m - 1);
        const float* agn = agg + (size_t)nrow * AGG_F;
        const float* inn = node_input + (size_t)nrow * NODE_F;

        // per-lane ovf tile range for this node: (o0>>4, (o1-1)>>4]
        int o0 = off[nrow], o1 = off[nrow + 1];
        int tA = (o0 >> 4) + 1;
        int tB = (o1 > o0) ? ((o1 - 1) >> 4) : (tA - 1);

        bf16x8 aggA[3], inS[2];
        #pragma unroll
        for (int kk = 0; kk < 3; ++kk)
            aggA[kk] = load8ovf(agn, ovf16, tA, tB, kk * 32 + lh * 8);
        #pragma unroll
        for (int kk = 0; kk < 2; ++kk) {
            const float* p0 = inn + kk * 32 + lh * 8;
            inS[kk] = cvt8(*(const float4*)p0, *(const float4*)(p0 + 4));
        }

        f32x4 convS[4], scS[4], angD = {0.f, 0.f, 0.f, 0.f};
        #pragma unroll
        for (int cb = 0; cb < 4; ++cb) {
            f32x4 a = {0.f, 0.f, 0.f, 0.f};
            #pragma unroll
            for (int kk = 0; kk < 3; ++kk) {
                bf16x8 b = *(const bf16x8*)&s_w2s[(((kk * 4 + lh) * 64) + cb * 16 + l15) * 8];
                a = __builtin_amdgcn_mfma_f32_16x16x32_bf16(aggA[kk], b, a, 0, 0, 0);
            }
            convS[cb] = a;
            f32x4 s = {0.f, 0.f, 0.f, 0.f};
            #pragma unroll
            for (int kk = 0; kk < 2; ++kk) {
                bf16x8 b = *(const bf16x8*)&s_wss[(((kk * 4 + lh) * 64) + cb * 16 + l15) * 8];
                s = __builtin_amdgcn_mfma_f32_16x16x32_bf16(inS[kk], b, s, 0, 0, 0);
            }
            scS[cb] = s;
        }
        #pragma unroll
        for (int kk = 0; kk < 3; ++kk) {
            bf16x8 b = *(const bf16x8*)&s_w3[(((kk * 4 + lh) * 16) + l15) * 8];
            angD = __builtin_amdgcn_mfma_f32_16x16x32_bf16(aggA[kk], b, angD, 0, 0, 0);
        }

        float attr[4], cs[4], sn[4];
        #pragma unroll
        for (int r = 0; r < 4; ++r) {
            attr[r] = node_attr[n0 + min(lh * 4 + r, m - 1)];
            float ang = __shfl(angD[r], lane & 48) * attr[r];
            cs[r] = cosf(ang);
            sn[r] = sinf(ang);
        }

        #pragma unroll
        for (int cb = 0; cb < 4; ++cb)
            #pragma unroll
            for (int r = 0; r < 4; ++r) {
                int node = lh * 4 + r;
                if (node < m)
                    out[(size_t)(n0 + node) * NODE_F + cb * 16 + l15] =
                        attr[r] * (cs[r] * scS[cb][r] + sn[r] * convS[cb][r]);
            }

        #pragma unroll
        for (int d = 0; d < 3; ++d) {
            bf16x8 aggV[3], inV;
            #pragma unroll
            for (int kk = 0; kk < 3; ++kk)
                aggV[kk] = load8ovf(agn, ovf16, tA, tB, 96 + d * 96 + kk * 32 + lh * 8);
            {
                float t[8];
                #pragma unroll
                for (int j = 0; j < 8; ++j)
                    t[j] = inn[64 + (lh * 8 + j) * 3 + d];
                inV = cvt8(make_float4(t[0], t[1], t[2], t[3]),
                           make_float4(t[4], t[5], t[6], t[7]));
            }
            #pragma unroll
            for (int cb = 0; cb < 2; ++cb) {
                f32x4 a = {0.f, 0.f, 0.f, 0.f};
                #pragma unroll
                for (int kk = 0; kk < 3; ++kk) {
                    bf16x8 b = *(const bf16x8*)&s_w2v[(((kk * 4 + lh) * 32) + cb * 16 + l15) * 8];
                    a = __builtin_amdgcn_mfma_f32_16x16x32_bf16(aggV[kk], b, a, 0, 0, 0);
                }
                f32x4 s = {0.f, 0.f, 0.f, 0.f};
                {
                    bf16x8 b = *(const bf16x8*)&s_wsv[((lh * 32) + cb * 16 + l15) * 8];
                    s = __builtin_amdgcn_mfma_f32_16x16x32_bf16(inV, b, s, 0, 0, 0);
                }
                #pragma unroll
                for (int r = 0; r < 4; ++r) {
                    int node = lh * 4 + r;
                    if (node < m)
                        out[(size_t)(n0 + node) * NODE_F + 64 + (cb * 16 + l15) * 3 + d] =
                            attr[r] * (cs[r] * s[r] + sn[r] * a[r]);
                }
            }
        }
    }
}

extern "C" void kernel_launch(void* const* d_in, const int* in_sizes, int n_in,
                              void* d_out, int out_size, void* d_ws, size_t ws_size,
                              hipStream_t stream)
{
    const float* node_input   = (const float*)d_in[0];
    const float* node_attr    = (const float*)d_in[1];
    const float* edge_attr    = (const float*)d_in[2];
    const float* edge_scalars = (const float*)d_in[3];
    const float* W_sc_s       = (const float*)d_in[4];
    const float* W_sc_v       = (const float*)d_in[5];
    const float* W1_s         = (const float*)d_in[6];
    const float* W1_v         = (const float*)d_in[7];
    const float* W2_s         = (const float*)d_in[8];
    const float* W2_v         = (const float*)d_in[9];
    const float* W3           = (const float*)d_in[10];
    const float* fcW1         = (const float*)d_in[11];
    const float* fcW2         = (const float*)d_in[12];
    const int*   edge_src     = (const int*)d_in[13];
    const int*   edge_dst     = (const int*)d_in[14];
    float* out = (float*)d_out;

    const int N = in_sizes[1];
    const int E = in_sizes[13];
    const int Np = (N + 3) & ~3;          // pad for int4 scan
    const int nwt = (E + 15) / 16;

    // ---- workspace layout (~83 MB) ----
    char* p = (char*)d_ws;
    float* agg = (float*)p;            p += (size_t)N * AGG_F * sizeof(float);
    int*   deg = (int*)p;              p += (size_t)Np * sizeof(int);
    int*   cur = (int*)p;              p += (size_t)Np * sizeof(int);
    int*   off = (int*)p;              p += (size_t)(Np + 4) * sizeof(int);
    int*   csr = (int*)p;              p += (size_t)E * sizeof(int);
    int*   bsum = (int*)p;             p += 64 * sizeof(int);
    p = (char*)(((size_t)p + 15) & ~(size_t)15);
    unsigned short* ovf16 = (unsigned short*)p;   // nwt * 384 bf16

    unsigned short* fbf = (unsigned short*)d_out;  // f lives in d_out (bf16), consumed before k_out

    hipMemsetAsync(deg, 0, (size_t)Np * sizeof(int), stream);

    int eb = (E + 255) / 256;
    k_count<<<eb, 256, 0, stream>>>(edge_dst, deg, E);

    int ng4 = (N + 3) >> 2;
    int nb = (ng4 + 1023) / 1024;
    k_scan_a<<<nb, 1024, 0, stream>>>(deg, off, bsum, N);
    k_scan_b<<<nb, 1024, 0, stream>>>(off, cur, bsum, agg, deg, N, nb);
    k_scatter<<<eb, 256, 0, stream>>>(edge_dst, cur, csr, E);

    int ntiles = (N + 15) / 16;
    int gridL = (ntiles + 3) / 4;
    k_node_lin<<<gridL, 256, 0, stream>>>(node_input, node_attr, W1_s, W1_v, fbf, N);

    int gridF = (nwt + 7) / 8;
    if (gridF > 1024) gridF = 1024;
    k_edge_fused<<<gridF, 512, 0, stream>>>(fbf, edge_scalars, edge_attr, fcW1, fcW2,
                                            edge_src, edge_dst, csr, off, agg, ovf16, E);

    int gridO = (ntiles + 3) / 4;
    if (gridO > 640) gridO = 640;
    k_out<<<gridO, 256, 0, stream>>>(node_input, node_attr, agg, ovf16, off,
                                     W_sc_s, W_sc_v, W2_s, W2_v, W3, out, N);
}